// Round 1
// baseline (661.446 us; speedup 1.0000x reference)
//
#include <hip/hip_runtime.h>
#include <hip/hip_bf16.h>

#define B_   8
#define DIM_ 512
#define T_   4096
#define H_   64
#define NC_  1024   // 2*B*H : cols 0..511 = eK*V (c=b*64+h), 512..1023 = eK

// ---------------------------------------------------------------------------
// K1: QKV projection.  grid (T/64, B), block 256.
// Computes Q[b][t][h] (ws), and S[t][c] with eK*V and eK packed for the GEMM.
// Per block: [64 h] x [64 t] tile for each of wq,wk,wv; 4x4 micro-tiles.
// ---------------------------------------------------------------------------
__global__ __launch_bounds__(256) void qkv_kernel(
    const float* __restrict__ x,
    const float* __restrict__ wq, const float* __restrict__ bq,
    const float* __restrict__ wk, const float* __restrict__ bk,
    const float* __restrict__ wv, const float* __restrict__ bv,
    float* __restrict__ Qbuf, float* __restrict__ Sbuf)
{
    __shared__ float xs[32][64];        // xs[dk][t]
    __shared__ float ws3[3][32][64];    // ws3[w][dk][h]; reused as st[64][65] in epilogue
    float* st = (float*)ws3;            // 64*65*4 = 16.6KB <= 24KB

    const int tid = threadIdx.x;
    const int b  = blockIdx.y;
    const int t0 = blockIdx.x * 64;
    const int i  = tid >> 4;            // h-group 0..15
    const int j  = tid & 15;            // t-group 0..15

    float acc[3][4][4];
#pragma unroll
    for (int w = 0; w < 3; w++)
#pragma unroll
        for (int p = 0; p < 4; p++)
#pragma unroll
            for (int q = 0; q < 4; q++) acc[w][p][q] = 0.f;

    const float* wptr[3] = {wq, wk, wv};

    for (int d0 = 0; d0 < DIM_; d0 += 32) {
        // x tile [32 d][64 t], coalesced along t
        {
            const int dk = tid >> 4;
            const int tt = (tid & 15) * 4;
            float4 v0 = *(const float4*)&x[((size_t)b * DIM_ + d0 + dk) * T_ + t0 + tt];
            float4 v1 = *(const float4*)&x[((size_t)b * DIM_ + d0 + dk + 16) * T_ + t0 + tt];
            *(float4*)&xs[dk][tt]      = v0;
            *(float4*)&xs[dk + 16][tt] = v1;
        }
        // w tiles [64 h][32 d] -> transposed LDS [dk][h]
#pragma unroll
        for (int w = 0; w < 3; w++) {
            const int hh  = tid >> 3;          // 0..31
            const int dk4 = (tid & 7) * 4;
#pragma unroll
            for (int pass = 0; pass < 2; pass++) {
                const int h = pass * 32 + hh;
                float4 v = *(const float4*)&wptr[w][(size_t)h * DIM_ + d0 + dk4];
                ws3[w][dk4 + 0][h] = v.x;
                ws3[w][dk4 + 1][h] = v.y;
                ws3[w][dk4 + 2][h] = v.z;
                ws3[w][dk4 + 3][h] = v.w;
            }
        }
        __syncthreads();
#pragma unroll
        for (int dk = 0; dk < 32; dk++) {
            float b4[4];
            *(float4*)b4 = *(const float4*)&xs[dk][j * 4];
#pragma unroll
            for (int w = 0; w < 3; w++) {
                float a4[4];
                *(float4*)a4 = *(const float4*)&ws3[w][dk][i * 4];
#pragma unroll
                for (int p = 0; p < 4; p++)
#pragma unroll
                    for (int q = 0; q < 4; q++) acc[w][p][q] += a4[p] * b4[q];
            }
        }
        __syncthreads();
    }

    // biases
    float bqv[4], bkv[4], bvv[4];
#pragma unroll
    for (int p = 0; p < 4; p++) {
        bqv[p] = bq[i * 4 + p];
        bkv[p] = bk[i * 4 + p];
        bvv[p] = bv[i * 4 + p];
    }
    float eK[4][4], Vv[4][4];
#pragma unroll
    for (int p = 0; p < 4; p++)
#pragma unroll
        for (int q = 0; q < 4; q++) {
            eK[p][q] = __expf(acc[1][p][q] + bkv[p]);
            Vv[p][q] = acc[2][p][q] + bvv[p];
        }

    const int STS = 65;
    const int lane = tid & 63;
    const int rr   = tid >> 6;

    // pass A: Q -> Qbuf[b][t][h]
#pragma unroll
    for (int p = 0; p < 4; p++)
#pragma unroll
        for (int q = 0; q < 4; q++)
            st[(j * 4 + q) * STS + (i * 4 + p)] = acc[0][p][q] + bqv[p];
    __syncthreads();
    for (int r0 = 0; r0 < 64; r0 += 4) {
        const int r = r0 + rr;
        Qbuf[((size_t)b * T_ + t0 + r) * H_ + lane] = st[r * STS + lane];
    }
    __syncthreads();

    // pass B: eK*V -> S[t][b*64+h]
#pragma unroll
    for (int p = 0; p < 4; p++)
#pragma unroll
        for (int q = 0; q < 4; q++)
            st[(j * 4 + q) * STS + (i * 4 + p)] = eK[p][q] * Vv[p][q];
    __syncthreads();
    for (int r0 = 0; r0 < 64; r0 += 4) {
        const int r = r0 + rr;
        Sbuf[(size_t)(t0 + r) * NC_ + b * 64 + lane] = st[r * STS + lane];
    }
    __syncthreads();

    // pass C: eK -> S[t][512 + b*64+h]
#pragma unroll
    for (int p = 0; p < 4; p++)
#pragma unroll
        for (int q = 0; q < 4; q++)
            st[(j * 4 + q) * STS + (i * 4 + p)] = eK[p][q];
    __syncthreads();
    for (int r0 = 0; r0 < 64; r0 += 4) {
        const int r = r0 + rr;
        Sbuf[(size_t)(t0 + r) * NC_ + 512 + b * 64 + lane] = st[r * STS + lane];
    }
}

// ---------------------------------------------------------------------------
// K2: ND[t][c] = sum_s exp(wbias[t][s]) * S[s][c].
// M=4096, N=1024, K=4096.  grid (N/64, M/64), block 256, 4x4 micro-tiles.
// ---------------------------------------------------------------------------
__global__ __launch_bounds__(256) void aft_gemm_kernel(
    const float* __restrict__ wbias, const float* __restrict__ Sbuf,
    float* __restrict__ ND)
{
    __shared__ float As[16][68];   // As[k][t]  (exp applied)
    __shared__ float Bs[16][68];   // Bs[k][c]

    const int tid = threadIdx.x;
    const int c0  = blockIdx.x * 64;
    const int t0  = blockIdx.y * 64;
    const int i   = tid >> 4;      // t-group
    const int j   = tid & 15;      // c-group

    float acc[4][4] = {};

    for (int s0 = 0; s0 < T_; s0 += 16) {
        {
            const int t  = tid >> 2;
            const int k4 = (tid & 3) * 4;
            float4 v = *(const float4*)&wbias[(size_t)(t0 + t) * T_ + s0 + k4];
            As[k4 + 0][t] = __expf(v.x);
            As[k4 + 1][t] = __expf(v.y);
            As[k4 + 2][t] = __expf(v.z);
            As[k4 + 3][t] = __expf(v.w);

            const int s  = tid >> 4;
            const int c4 = (tid & 15) * 4;
            float4 u = *(const float4*)&Sbuf[(size_t)(s0 + s) * NC_ + c0 + c4];
            *(float4*)&Bs[s][c4] = u;
        }
        __syncthreads();
#pragma unroll
        for (int k = 0; k < 16; k++) {
            float a4[4], b4[4];
            *(float4*)a4 = *(const float4*)&As[k][i * 4];
            *(float4*)b4 = *(const float4*)&Bs[k][j * 4];
#pragma unroll
            for (int p = 0; p < 4; p++)
#pragma unroll
                for (int q = 0; q < 4; q++) acc[p][q] += a4[p] * b4[q];
        }
        __syncthreads();
    }
#pragma unroll
    for (int p = 0; p < 4; p++) {
        float4 v = {acc[p][0], acc[p][1], acc[p][2], acc[p][3]};
        *(float4*)&ND[(size_t)(t0 + i * 4 + p) * NC_ + c0 + j * 4] = v;
    }
}

// ---------------------------------------------------------------------------
// K3: y = sigmoid(Q)*num/den; out[b][t][d] = y @ wp.T + bp.
// grid (T/32, B), block 256.
// ---------------------------------------------------------------------------
__global__ __launch_bounds__(256) void epilogue_kernel(
    const float* __restrict__ Qbuf, const float* __restrict__ ND,
    const float* __restrict__ wp, const float* __restrict__ bp,
    float* __restrict__ out, int write_both)
{
    __shared__ float ysT[64][36];    // ysT[h][t]
    __shared__ float wpL[64][132];   // wpL[h][d-in-chunk]

    const int tid  = threadIdx.x;
    const int t0   = blockIdx.x * 32;
    const int b    = blockIdx.y;
    const int lane = tid & 63;
    const int trow = tid >> 6;

    for (int pass = 0; pass < 8; pass++) {
        const int t = pass * 4 + trow;
        float q   = Qbuf[((size_t)b * T_ + t0 + t) * H_ + lane];
        float num = ND[(size_t)(t0 + t) * NC_ + b * 64 + lane];
        float den = ND[(size_t)(t0 + t) * NC_ + 512 + b * 64 + lane];
        float y = (1.f / (1.f + __expf(-q))) * num / den;
        ysT[lane][t] = y;
    }

    const int i = tid >> 5;   // t-group 0..7
    const int j = tid & 31;   // d-group 0..31

    for (int dc = 0; dc < 4; dc++) {
        __syncthreads();   // ysT ready (dc=0) / wpL reuse safe (dc>0)
        for (int pass = 0; pass < 8; pass++) {
            const int row = pass * 16 + (tid >> 4);
            const int h4  = (tid & 15) * 4;
            float4 v = *(const float4*)&wp[(size_t)(dc * 128 + row) * H_ + h4];
            wpL[h4 + 0][row] = v.x;
            wpL[h4 + 1][row] = v.y;
            wpL[h4 + 2][row] = v.z;
            wpL[h4 + 3][row] = v.w;
        }
        __syncthreads();

        float acc[4][4] = {};
#pragma unroll
        for (int h = 0; h < 64; h++) {
            float a4[4], b4[4];
            *(float4*)a4 = *(const float4*)&ysT[h][i * 4];
            *(float4*)b4 = *(const float4*)&wpL[h][j * 4];
#pragma unroll
            for (int p = 0; p < 4; p++)
#pragma unroll
                for (int q = 0; q < 4; q++) acc[p][q] += a4[p] * b4[q];
        }
#pragma unroll
        for (int p = 0; p < 4; p++) {
            const int t = t0 + i * 4 + p;
            const int d = dc * 128 + j * 4;
            float4 bpv = *(const float4*)&bp[d];
            float4 v = {acc[p][0] + bpv.x, acc[p][1] + bpv.y,
                        acc[p][2] + bpv.z, acc[p][3] + bpv.w};
            *(float4*)&out[((size_t)b * T_ + t) * DIM_ + d] = v;
            if (write_both)
                *(float4*)&out[(size_t)B_ * T_ * DIM_ + ((size_t)b * T_ + t) * DIM_ + d] = v;
        }
    }
}

// ---------------------------------------------------------------------------
// K4: duplicate copy1 -> copy2 (only when scratch lived in copy2's region)
// ---------------------------------------------------------------------------
__global__ void dup_kernel(const float4* __restrict__ src, float4* __restrict__ dst, int n4)
{
    int idx = blockIdx.x * blockDim.x + threadIdx.x;
    int stride = gridDim.x * blockDim.x;
    for (int k = idx; k < n4; k += stride) dst[k] = src[k];
}

extern "C" void kernel_launch(void* const* d_in, const int* in_sizes, int n_in,
                              void* d_out, int out_size, void* d_ws, size_t ws_size,
                              hipStream_t stream)
{
    const float* x     = (const float*)d_in[0];
    const float* wq    = (const float*)d_in[1];
    const float* bq    = (const float*)d_in[2];
    const float* wk    = (const float*)d_in[3];
    const float* bk    = (const float*)d_in[4];
    const float* wv    = (const float*)d_in[5];
    const float* bv    = (const float*)d_in[6];
    const float* wp    = (const float*)d_in[7];
    const float* bp    = (const float*)d_in[8];
    const float* wbias = (const float*)d_in[9];
    float* out = (float*)d_out;

    const size_t SZ_COPY = (size_t)B_ * T_ * DIM_;   // 16,777,216 floats
    const size_t SZ_S    = (size_t)T_ * NC_;         //  4,194,304 floats
    const size_t SZ_Q    = (size_t)B_ * T_ * H_;     //  2,097,152 floats
    const size_t need    = (2 * SZ_S + SZ_Q) * sizeof(float);  // ~42 MB

    float *Sbuf, *NDbuf, *Qbuf;
    int write_both;
    if (ws_size >= need) {
        float* w = (float*)d_ws;
        Sbuf = w; NDbuf = w + SZ_S; Qbuf = w + 2 * SZ_S;
        write_both = 1;
    } else {
        // stash scratch in the (not-yet-written) second output copy
        float* base = out + SZ_COPY;
        Sbuf = base; NDbuf = base + SZ_S; Qbuf = base + 2 * SZ_S;
        write_both = 0;
    }

    qkv_kernel<<<dim3(T_ / 64, B_), 256, 0, stream>>>(x, wq, bq, wk, bk, wv, bv, Qbuf, Sbuf);
    aft_gemm_kernel<<<dim3(NC_ / 64, T_ / 64), 256, 0, stream>>>(wbias, Sbuf, NDbuf);
    epilogue_kernel<<<dim3(T_ / 32, B_), 256, 0, stream>>>(Qbuf, NDbuf, wp, bp, out, write_both);
    if (!write_both)
        dup_kernel<<<2048, 256, 0, stream>>>((const float4*)out,
                                             (float4*)(out + SZ_COPY),
                                             (int)(SZ_COPY / 4));
}

// Round 2
// 254.082 us; speedup vs baseline: 2.6033x; 2.6033x over previous
//
#include <hip/hip_runtime.h>
#include <hip/hip_bf16.h>

#define B_   8
#define DIM_ 512
#define T_   4096
#define H_   64
#define NC_  1024   // 2*B*H : cols 0..511 = eK*V (c=b*64+h), 512..1023 = eK

typedef __attribute__((ext_vector_type(8))) short short8;
typedef __attribute__((ext_vector_type(4))) float f32x4;

__device__ __forceinline__ unsigned short f2bf(float x) {
    __hip_bfloat16 h = __float2bfloat16(x);
    return *reinterpret_cast<unsigned short*>(&h);
}
__device__ __forceinline__ float bf2f(unsigned short u) {
    __hip_bfloat16 h = *reinterpret_cast<__hip_bfloat16*>(&u);
    return __bfloat162float(h);
}
__device__ __forceinline__ void gload16(const void* g, void* l) {
    __builtin_amdgcn_global_load_lds(
        (const __attribute__((address_space(1))) unsigned int*)g,
        (__attribute__((address_space(3))) unsigned int*)l, 16, 0, 0);
}

// ---------------------------------------------------------------------------
// K0: Aexp[t][s] = bf16(exp(wbias[t][s]))
// ---------------------------------------------------------------------------
__global__ __launch_bounds__(256) void ewb_kernel(
    const float* __restrict__ wb, unsigned short* __restrict__ Aexp)
{
    const int n4 = T_ * T_ / 4;
    int idx = blockIdx.x * blockDim.x + threadIdx.x;
    int stride = gridDim.x * blockDim.x;
    for (int i = idx; i < n4; i += stride) {
        float4 v = ((const float4*)wb)[i];
        ushort4 o;
        o.x = f2bf(__expf(v.x));
        o.y = f2bf(__expf(v.y));
        o.z = f2bf(__expf(v.z));
        o.w = f2bf(__expf(v.w));
        ((ushort4*)Aexp)[i] = o;
    }
}

// ---------------------------------------------------------------------------
// K1: QKV projection.  grid (T/64, B), block 256.
// Q[b][t][h] fp32 -> Qbuf;  SbT[c][t] bf16 (c-major, GEMM B-operand layout):
//   row c = b*64+h      : eK*V
//   row c = 512+b*64+h  : eK
// ---------------------------------------------------------------------------
__global__ __launch_bounds__(256) void qkv_kernel(
    const float* __restrict__ x,
    const float* __restrict__ wq, const float* __restrict__ bq,
    const float* __restrict__ wk, const float* __restrict__ bk,
    const float* __restrict__ wv, const float* __restrict__ bv,
    float* __restrict__ Qbuf, unsigned short* __restrict__ SbT)
{
    __shared__ float xs[32][64];        // xs[dk][t]
    __shared__ float ws3[3][32][64];    // ws3[w][dk][h]; reused as st[64][65]
    float* st = (float*)ws3;

    const int tid = threadIdx.x;
    const int b  = blockIdx.y;
    const int t0 = blockIdx.x * 64;
    const int i  = tid >> 4;            // h-group 0..15
    const int j  = tid & 15;            // t-group 0..15

    float acc[3][4][4];
#pragma unroll
    for (int w = 0; w < 3; w++)
#pragma unroll
        for (int p = 0; p < 4; p++)
#pragma unroll
            for (int q = 0; q < 4; q++) acc[w][p][q] = 0.f;

    const float* wptr[3] = {wq, wk, wv};

    for (int d0 = 0; d0 < DIM_; d0 += 32) {
        {
            const int dk = tid >> 4;
            const int tt = (tid & 15) * 4;
            float4 v0 = *(const float4*)&x[((size_t)b * DIM_ + d0 + dk) * T_ + t0 + tt];
            float4 v1 = *(const float4*)&x[((size_t)b * DIM_ + d0 + dk + 16) * T_ + t0 + tt];
            *(float4*)&xs[dk][tt]      = v0;
            *(float4*)&xs[dk + 16][tt] = v1;
        }
#pragma unroll
        for (int w = 0; w < 3; w++) {
            const int hh  = tid >> 3;
            const int dk4 = (tid & 7) * 4;
#pragma unroll
            for (int pass = 0; pass < 2; pass++) {
                const int h = pass * 32 + hh;
                float4 v = *(const float4*)&wptr[w][(size_t)h * DIM_ + d0 + dk4];
                ws3[w][dk4 + 0][h] = v.x;
                ws3[w][dk4 + 1][h] = v.y;
                ws3[w][dk4 + 2][h] = v.z;
                ws3[w][dk4 + 3][h] = v.w;
            }
        }
        __syncthreads();
#pragma unroll
        for (int dk = 0; dk < 32; dk++) {
            float b4[4];
            *(float4*)b4 = *(const float4*)&xs[dk][j * 4];
#pragma unroll
            for (int w = 0; w < 3; w++) {
                float a4[4];
                *(float4*)a4 = *(const float4*)&ws3[w][dk][i * 4];
#pragma unroll
                for (int p = 0; p < 4; p++)
#pragma unroll
                    for (int q = 0; q < 4; q++) acc[w][p][q] += a4[p] * b4[q];
            }
        }
        __syncthreads();
    }

    float bqv[4], bkv[4], bvv[4];
#pragma unroll
    for (int p = 0; p < 4; p++) {
        bqv[p] = bq[i * 4 + p];
        bkv[p] = bk[i * 4 + p];
        bvv[p] = bv[i * 4 + p];
    }
    float eK[4][4], Vv[4][4];
#pragma unroll
    for (int p = 0; p < 4; p++)
#pragma unroll
        for (int q = 0; q < 4; q++) {
            eK[p][q] = __expf(acc[1][p][q] + bkv[p]);
            Vv[p][q] = acc[2][p][q] + bvv[p];
        }

    // Q -> Qbuf (fp32) via LDS transpose for coalescing
    const int STS = 65;
    const int lane = tid & 63;
    const int rr   = tid >> 6;
#pragma unroll
    for (int p = 0; p < 4; p++)
#pragma unroll
        for (int q = 0; q < 4; q++)
            st[(j * 4 + q) * STS + (i * 4 + p)] = acc[0][p][q] + bqv[p];
    __syncthreads();
    for (int r0 = 0; r0 < 64; r0 += 4) {
        const int r = r0 + rr;
        Qbuf[((size_t)b * T_ + t0 + r) * H_ + lane] = st[r * STS + lane];
    }

    // SbT: direct bf16 stores, 4 consecutive t per thread (8B packed)
#pragma unroll
    for (int p = 0; p < 4; p++) {
        const int h = i * 4 + p;
        ushort4 pk, pe;
        pk.x = f2bf(eK[p][0] * Vv[p][0]);
        pk.y = f2bf(eK[p][1] * Vv[p][1]);
        pk.z = f2bf(eK[p][2] * Vv[p][2]);
        pk.w = f2bf(eK[p][3] * Vv[p][3]);
        pe.x = f2bf(eK[p][0]);
        pe.y = f2bf(eK[p][1]);
        pe.z = f2bf(eK[p][2]);
        pe.w = f2bf(eK[p][3]);
        *(ushort4*)&SbT[(size_t)(b * 64 + h) * T_ + t0 + j * 4] = pk;
        *(ushort4*)&SbT[(size_t)(512 + b * 64 + h) * T_ + t0 + j * 4] = pe;
    }
}

// ---------------------------------------------------------------------------
// K2: ND[ks][t][c] = sum_{s in half ks} Aexp[t][s] * SbT[c][s]   (bf16 MFMA)
// 128x128 tile, BK=64, 4 waves (2x2), 16x16x32 MFMA, split-K=2.
// grid (NC/128, T/128, 2), block 256.
// ---------------------------------------------------------------------------
__global__ __launch_bounds__(256) void aft_gemm_mfma(
    const unsigned short* __restrict__ Aexp,
    const unsigned short* __restrict__ SbT,
    unsigned short* __restrict__ ND)
{
    __shared__ unsigned short As[128 * 64];   // [t'][k]
    __shared__ unsigned short Bs[128 * 64];   // [c'][k]

    const int tid = threadIdx.x;
    const int c0 = blockIdx.x * 128;
    const int t0 = blockIdx.y * 128;
    const int ks = blockIdx.z;
    const int sbase = ks * (T_ / 2);

    const int wid = tid >> 6, lane = tid & 63;
    const int wm = wid >> 1, wn = wid & 1;

    f32x4 acc[4][4];
    const f32x4 vzero = {0.f, 0.f, 0.f, 0.f};
#pragma unroll
    for (int a = 0; a < 4; a++)
#pragma unroll
        for (int b2 = 0; b2 < 4; b2++) acc[a][b2] = vzero;

    const int rs  = tid >> 3;         // staging row 0..31
    const int ks8 = (tid & 7) * 8;    // staging col (8 bf16 = 16B)
    const unsigned short* Ag = Aexp + (size_t)(t0 + rs) * T_ + sbase + ks8;
    const unsigned short* Bg = SbT  + (size_t)(c0 + rs) * T_ + sbase + ks8;

    for (int s0 = 0; s0 < T_ / 2; s0 += 64) {
#pragma unroll
        for (int it = 0; it < 4; it++) {
            gload16(Ag + (size_t)(it * 32) * T_ + s0, (void*)&As[(it * 256 + tid) * 8]);
            gload16(Bg + (size_t)(it * 32) * T_ + s0, (void*)&Bs[(it * 256 + tid) * 8]);
        }
        __syncthreads();
        const int row_a = wm * 64 + (lane & 15);
        const int row_b = wn * 64 + (lane & 15);
#pragma unroll
        for (int kk = 0; kk < 2; kk++) {
            const int kr = kk * 32 + (lane >> 4) * 8;
            short8 af[4], bfr[4];
#pragma unroll
            for (int f = 0; f < 4; f++)
                af[f] = *(const short8*)&As[(row_a + f * 16) * 64 + kr];
#pragma unroll
            for (int f = 0; f < 4; f++)
                bfr[f] = *(const short8*)&Bs[(row_b + f * 16) * 64 + kr];
#pragma unroll
            for (int fm = 0; fm < 4; fm++)
#pragma unroll
                for (int fn = 0; fn < 4; fn++)
                    acc[fm][fn] = __builtin_amdgcn_mfma_f32_16x16x32_bf16(
                        af[fm], bfr[fn], acc[fm][fn], 0, 0, 0);
        }
        __syncthreads();
    }

    unsigned short* NDp = ND + (size_t)ks * T_ * NC_;
    const int r4 = (lane >> 4) * 4;
    const int cc = lane & 15;
#pragma unroll
    for (int fm = 0; fm < 4; fm++)
#pragma unroll
        for (int fn = 0; fn < 4; fn++)
#pragma unroll
            for (int r = 0; r < 4; r++) {
                const int t = t0 + wm * 64 + fm * 16 + r4 + r;
                const int c = c0 + wn * 64 + fn * 16 + cc;
                NDp[(size_t)t * NC_ + c] = f2bf(acc[fm][fn][r]);
            }
}

// ---------------------------------------------------------------------------
// K3: y = sigmoid(Q)*num/den; out[b][t][d] = y @ wp.T + bp.
// grid (T/32, B), block 256.  ND is bf16, 2 split-K parts summed here.
// ---------------------------------------------------------------------------
__global__ __launch_bounds__(256) void epilogue_kernel(
    const float* __restrict__ Qbuf, const unsigned short* __restrict__ ND,
    const float* __restrict__ wp, const float* __restrict__ bp,
    float* __restrict__ out, int write_both)
{
    __shared__ float ysT[64][36];
    __shared__ float wpL[64][132];

    const int tid  = threadIdx.x;
    const int t0   = blockIdx.x * 32;
    const int b    = blockIdx.y;
    const int lane = tid & 63;
    const int trow = tid >> 6;
    const unsigned short* ND1 = ND + (size_t)T_ * NC_;

    for (int pass = 0; pass < 8; pass++) {
        const int t = pass * 4 + trow;
        float q   = Qbuf[((size_t)b * T_ + t0 + t) * H_ + lane];
        float num = bf2f(ND [(size_t)(t0 + t) * NC_ + b * 64 + lane])
                  + bf2f(ND1[(size_t)(t0 + t) * NC_ + b * 64 + lane]);
        float den = bf2f(ND [(size_t)(t0 + t) * NC_ + 512 + b * 64 + lane])
                  + bf2f(ND1[(size_t)(t0 + t) * NC_ + 512 + b * 64 + lane]);
        float y = (1.f / (1.f + __expf(-q))) * num / den;
        ysT[lane][t] = y;
    }

    const int i = tid >> 5;
    const int j = tid & 31;

    for (int dc = 0; dc < 4; dc++) {
        __syncthreads();
        for (int pass = 0; pass < 8; pass++) {
            const int row = pass * 16 + (tid >> 4);
            const int h4  = (tid & 15) * 4;
            float4 v = *(const float4*)&wp[(size_t)(dc * 128 + row) * H_ + h4];
            wpL[h4 + 0][row] = v.x;
            wpL[h4 + 1][row] = v.y;
            wpL[h4 + 2][row] = v.z;
            wpL[h4 + 3][row] = v.w;
        }
        __syncthreads();

        float acc[4][4] = {};
#pragma unroll
        for (int h = 0; h < 64; h++) {
            float a4[4], b4[4];
            *(float4*)a4 = *(const float4*)&ysT[h][i * 4];
            *(float4*)b4 = *(const float4*)&wpL[h][j * 4];
#pragma unroll
            for (int p = 0; p < 4; p++)
#pragma unroll
                for (int q = 0; q < 4; q++) acc[p][q] += a4[p] * b4[q];
        }
#pragma unroll
        for (int p = 0; p < 4; p++) {
            const int t = t0 + i * 4 + p;
            const int d = dc * 128 + j * 4;
            float4 bpv = *(const float4*)&bp[d];
            float4 v = {acc[p][0] + bpv.x, acc[p][1] + bpv.y,
                        acc[p][2] + bpv.z, acc[p][3] + bpv.w};
            *(float4*)&out[((size_t)b * T_ + t) * DIM_ + d] = v;
            if (write_both)
                *(float4*)&out[(size_t)B_ * T_ * DIM_ + ((size_t)b * T_ + t) * DIM_ + d] = v;
        }
    }
}

__global__ void dup_kernel(const float4* __restrict__ src, float4* __restrict__ dst, int n4)
{
    int idx = blockIdx.x * blockDim.x + threadIdx.x;
    int stride = gridDim.x * blockDim.x;
    for (int k = idx; k < n4; k += stride) dst[k] = src[k];
}

extern "C" void kernel_launch(void* const* d_in, const int* in_sizes, int n_in,
                              void* d_out, int out_size, void* d_ws, size_t ws_size,
                              hipStream_t stream)
{
    const float* x     = (const float*)d_in[0];
    const float* wq    = (const float*)d_in[1];
    const float* bq    = (const float*)d_in[2];
    const float* wk    = (const float*)d_in[3];
    const float* bk    = (const float*)d_in[4];
    const float* wv    = (const float*)d_in[5];
    const float* bv    = (const float*)d_in[6];
    const float* wp    = (const float*)d_in[7];
    const float* bp    = (const float*)d_in[8];
    const float* wbias = (const float*)d_in[9];
    float* out = (float*)d_out;

    const size_t SZ_COPY = (size_t)B_ * T_ * DIM_;   // floats per output copy

    // scratch layout (bytes):
    //   Aexp  bf16 [4096][4096]   33,554,432
    //   SbT   bf16 [1024][4096]    8,388,608
    //   Qbuf  f32  [8][4096][64]   8,388,608
    //   ND    bf16 [2][4096][1024] 16,777,216   total = 67,108,864
    const size_t NEED = 67108864;
    char* R;
    int write_both;
    if (ws_size >= NEED) {
        R = (char*)d_ws;
        write_both = 1;
    } else {
        R = (char*)(out + SZ_COPY);   // stash in not-yet-written second copy
        write_both = 0;
    }
    unsigned short* Aexp  = (unsigned short*)R;
    unsigned short* SbT   = (unsigned short*)(R + 33554432);
    float*          Qbuf  = (float*)(R + 41943040);
    unsigned short* NDbuf = (unsigned short*)(R + 50331648);

    ewb_kernel<<<2048, 256, 0, stream>>>(wbias, Aexp);
    qkv_kernel<<<dim3(T_ / 64, B_), 256, 0, stream>>>(x, wq, bq, wk, bk, wv, bv, Qbuf, SbT);
    aft_gemm_mfma<<<dim3(NC_ / 128, T_ / 128, 2), 256, 0, stream>>>(Aexp, SbT, NDbuf);
    epilogue_kernel<<<dim3(T_ / 32, B_), 256, 0, stream>>>(Qbuf, NDbuf, wp, bp, out, write_both);
    if (!write_both)
        dup_kernel<<<2048, 256, 0, stream>>>((const float4*)out,
                                             (float4*)(out + SZ_COPY),
                                             (int)(SZ_COPY / 4));
}

// Round 3
// 212.964 us; speedup vs baseline: 3.1059x; 1.1931x over previous
//
#include <hip/hip_runtime.h>
#include <hip/hip_bf16.h>

#define B_   8
#define DIM_ 512
#define T_   4096
#define H_   64
#define NC_  1024   // 2*B*H : cols 0..511 = eK*V (c=b*64+h), 512..1023 = eK

typedef __attribute__((ext_vector_type(8))) short short8;
typedef __attribute__((ext_vector_type(4))) float f32x4;

__device__ __forceinline__ unsigned short f2bf(float x) {
    __hip_bfloat16 h = __float2bfloat16(x);
    return *reinterpret_cast<unsigned short*>(&h);
}
__device__ __forceinline__ float bf2f(unsigned short u) {
    __hip_bfloat16 h = *reinterpret_cast<__hip_bfloat16*>(&u);
    return __bfloat162float(h);
}
__device__ __forceinline__ void gload16(const void* g, void* l) {
    __builtin_amdgcn_global_load_lds(
        (const __attribute__((address_space(1))) unsigned int*)g,
        (__attribute__((address_space(3))) unsigned int*)l, 16, 0, 0);
}

// ---------------------------------------------------------------------------
// K0: Aexp[t][s] = bf16(exp(wbias[t][s]))
// ---------------------------------------------------------------------------
__global__ __launch_bounds__(256) void ewb_kernel(
    const float* __restrict__ wb, unsigned short* __restrict__ Aexp)
{
    const int n4 = T_ * T_ / 4;
    int idx = blockIdx.x * blockDim.x + threadIdx.x;
    int stride = gridDim.x * blockDim.x;
    for (int i = idx; i < n4; i += stride) {
        float4 v = ((const float4*)wb)[i];
        ushort4 o;
        o.x = f2bf(__expf(v.x));
        o.y = f2bf(__expf(v.y));
        o.z = f2bf(__expf(v.z));
        o.w = f2bf(__expf(v.w));
        ((ushort4*)Aexp)[i] = o;
    }
}

// ---------------------------------------------------------------------------
// K0b: Wcat[192][512] bf16 from {wq,wk,wv}; bcat[192] f32 from {bq,bk,bv}.
// grid (192), block 128.
// ---------------------------------------------------------------------------
__global__ __launch_bounds__(128) void wcat_kernel(
    const float* __restrict__ wq, const float* __restrict__ bq,
    const float* __restrict__ wk, const float* __restrict__ bk,
    const float* __restrict__ wv, const float* __restrict__ bv,
    unsigned short* __restrict__ Wcat, float* __restrict__ bcat)
{
    const int r = blockIdx.x;
    const int tid = threadIdx.x;
    const float* src = (r < 64) ? (wq + (size_t)r * DIM_)
                     : (r < 128) ? (wk + (size_t)(r - 64) * DIM_)
                                 : (wv + (size_t)(r - 128) * DIM_);
    const int d4 = tid * 4;
    float4 v = *(const float4*)&src[d4];
    ushort4 o;
    o.x = f2bf(v.x); o.y = f2bf(v.y); o.z = f2bf(v.z); o.w = f2bf(v.w);
    *(ushort4*)&Wcat[(size_t)r * DIM_ + d4] = o;
    if (tid == 0)
        bcat[r] = (r < 64) ? bq[r] : (r < 128) ? bk[r - 64] : bv[r - 128];
}

// ---------------------------------------------------------------------------
// K1a: transpose one 4-batch chunk of x: [4][512][4096] f32 -> xT [4][4096][512] bf16
// grid (T/64, DIM/64, 4), block 256.
// ---------------------------------------------------------------------------
__global__ __launch_bounds__(256) void xpose_kernel(
    const float* __restrict__ x, unsigned short* __restrict__ xT, int b0)
{
    __shared__ float st[64 * 65];
    const int tid = threadIdx.x;
    const int t0 = blockIdx.x * 64;
    const int d0 = blockIdx.y * 64;
    const int bl = blockIdx.z;           // local batch 0..3
    const int b  = b0 + bl;

#pragma unroll
    for (int p = 0; p < 4; p++) {
        const int d  = p * 16 + (tid >> 4);
        const int t4 = (tid & 15) * 4;
        float4 v = *(const float4*)&x[((size_t)b * DIM_ + d0 + d) * T_ + t0 + t4];
        *(float4*)&st[d * 65 + t4] = v;
    }
    __syncthreads();
#pragma unroll
    for (int p = 0; p < 2; p++) {
        const int t  = p * 32 + (tid >> 3);
        const int d8 = (tid & 7) * 8;
        union { ushort u[8]; uint4 v; } pk;
#pragma unroll
        for (int jj = 0; jj < 8; jj++)
            pk.u[jj] = f2bf(st[(d8 + jj) * 65 + t]);
        *(uint4*)&xT[((size_t)bl * T_ + t0 + t) * DIM_ + d0 + d8] = pk.v;
    }
}

// ---------------------------------------------------------------------------
// K1b: QKV via MFMA.  grid (T/64, 4), block 256 (4 waves, each 16 t-rows x 192 h).
// C[t][h'] = sum_d xT[t][d] * Wcat[h'][d];  h'=0..63 Q, 64..127 K, 128..191 V.
// Writes Qbuf bf16 [b][t][64], SbT bf16 [c][t].
// ---------------------------------------------------------------------------
__global__ __launch_bounds__(256) void qkv_mfma(
    const unsigned short* __restrict__ xT, const unsigned short* __restrict__ Wcat,
    const float* __restrict__ bcat,
    unsigned short* __restrict__ Qb, unsigned short* __restrict__ SbT, int b0)
{
    __shared__ unsigned short As[64 * 64];    // [t'][d]
    __shared__ unsigned short Bs[192 * 64];   // [h'][d]

    const int tid = threadIdx.x;
    const int t0 = blockIdx.x * 64;
    const int bl = blockIdx.y;               // local batch 0..3
    const int b  = b0 + bl;
    const int wid = tid >> 6, lane = tid & 63;

    f32x4 acc[12];
    const f32x4 vzero = {0.f, 0.f, 0.f, 0.f};
#pragma unroll
    for (int f = 0; f < 12; f++) acc[f] = vzero;

    const int rs  = tid >> 3;        // 0..31
    const int ks8 = (tid & 7) * 8;
    const unsigned short* Ag = xT + ((size_t)bl * T_ + t0 + rs) * DIM_ + ks8;
    const unsigned short* Bg = Wcat + (size_t)rs * DIM_ + ks8;

    for (int d0 = 0; d0 < DIM_; d0 += 64) {
#pragma unroll
        for (int it = 0; it < 2; it++)
            gload16(Ag + (size_t)(it * 32) * DIM_ + d0, (void*)&As[(it * 256 + tid) * 8]);
#pragma unroll
        for (int it = 0; it < 6; it++)
            gload16(Bg + (size_t)(it * 32) * DIM_ + d0, (void*)&Bs[(it * 256 + tid) * 8]);
        __syncthreads();
        const int row_a = wid * 16 + (lane & 15);
#pragma unroll
        for (int kk = 0; kk < 2; kk++) {
            const int kr = kk * 32 + (lane >> 4) * 8;
            short8 af = *(const short8*)&As[row_a * 64 + kr];
#pragma unroll
            for (int fn = 0; fn < 12; fn++) {
                short8 bf = *(const short8*)&Bs[(fn * 16 + (lane & 15)) * 64 + kr];
                acc[fn] = __builtin_amdgcn_mfma_f32_16x16x32_bf16(af, bf, acc[fn], 0, 0, 0);
            }
        }
        __syncthreads();
    }

    const int cc = lane & 15;
    const int t_base = t0 + wid * 16 + (lane >> 4) * 4;

    // Q (fn 0..3) -> Qbuf bf16
#pragma unroll
    for (int fn = 0; fn < 4; fn++) {
        const int h = fn * 16 + cc;
        const float bb = bcat[h];
#pragma unroll
        for (int r = 0; r < 4; r++)
            Qb[((size_t)b * T_ + t_base + r) * H_ + h] = f2bf(acc[fn][r] + bb);
    }
    // K (fn 4..7) + V (fn 8..11) -> SbT
#pragma unroll
    for (int f = 0; f < 4; f++) {
        const int h = f * 16 + cc;
        const float bK = bcat[64 + h];
        const float bV = bcat[128 + h];
        ushort4 pk, pe;
        float e0 = __expf(acc[4 + f][0] + bK), v0 = acc[8 + f][0] + bV;
        float e1 = __expf(acc[4 + f][1] + bK), v1 = acc[8 + f][1] + bV;
        float e2 = __expf(acc[4 + f][2] + bK), v2 = acc[8 + f][2] + bV;
        float e3 = __expf(acc[4 + f][3] + bK), v3 = acc[8 + f][3] + bV;
        pe.x = f2bf(e0); pe.y = f2bf(e1); pe.z = f2bf(e2); pe.w = f2bf(e3);
        pk.x = f2bf(e0 * v0); pk.y = f2bf(e1 * v1); pk.z = f2bf(e2 * v2); pk.w = f2bf(e3 * v3);
        *(ushort4*)&SbT[(size_t)(b * 64 + h) * T_ + t_base] = pk;
        *(ushort4*)&SbT[(size_t)(512 + b * 64 + h) * T_ + t_base] = pe;
    }
}

// ---------------------------------------------------------------------------
// K2: ND[ks][t][c] = sum_{s in half ks} Aexp[t][s] * SbT[c][s]   (bf16 MFMA)
// 128x128 tile, BK=64, 4 waves (2x2), 16x16x32 MFMA, split-K=2.
// grid (NC/128, T/128, 2), block 256.
// ---------------------------------------------------------------------------
__global__ __launch_bounds__(256) void aft_gemm_mfma(
    const unsigned short* __restrict__ Aexp,
    const unsigned short* __restrict__ SbT,
    unsigned short* __restrict__ ND)
{
    __shared__ unsigned short As[128 * 64];   // [t'][k]
    __shared__ unsigned short Bs[128 * 64];   // [c'][k]

    const int tid = threadIdx.x;
    const int c0 = blockIdx.x * 128;
    const int t0 = blockIdx.y * 128;
    const int ks = blockIdx.z;
    const int sbase = ks * (T_ / 2);

    const int wid = tid >> 6, lane = tid & 63;
    const int wm = wid >> 1, wn = wid & 1;

    f32x4 acc[4][4];
    const f32x4 vzero = {0.f, 0.f, 0.f, 0.f};
#pragma unroll
    for (int a = 0; a < 4; a++)
#pragma unroll
        for (int b2 = 0; b2 < 4; b2++) acc[a][b2] = vzero;

    const int rs  = tid >> 3;
    const int ks8 = (tid & 7) * 8;
    const unsigned short* Ag = Aexp + (size_t)(t0 + rs) * T_ + sbase + ks8;
    const unsigned short* Bg = SbT  + (size_t)(c0 + rs) * T_ + sbase + ks8;

    for (int s0 = 0; s0 < T_ / 2; s0 += 64) {
#pragma unroll
        for (int it = 0; it < 4; it++) {
            gload16(Ag + (size_t)(it * 32) * T_ + s0, (void*)&As[(it * 256 + tid) * 8]);
            gload16(Bg + (size_t)(it * 32) * T_ + s0, (void*)&Bs[(it * 256 + tid) * 8]);
        }
        __syncthreads();
        const int row_a = wm * 64 + (lane & 15);
        const int row_b = wn * 64 + (lane & 15);
#pragma unroll
        for (int kk = 0; kk < 2; kk++) {
            const int kr = kk * 32 + (lane >> 4) * 8;
            short8 af[4], bfr[4];
#pragma unroll
            for (int f = 0; f < 4; f++)
                af[f] = *(const short8*)&As[(row_a + f * 16) * 64 + kr];
#pragma unroll
            for (int f = 0; f < 4; f++)
                bfr[f] = *(const short8*)&Bs[(row_b + f * 16) * 64 + kr];
#pragma unroll
            for (int fm = 0; fm < 4; fm++)
#pragma unroll
                for (int fn = 0; fn < 4; fn++)
                    acc[fm][fn] = __builtin_amdgcn_mfma_f32_16x16x32_bf16(
                        af[fm], bfr[fn], acc[fm][fn], 0, 0, 0);
        }
        __syncthreads();
    }

    unsigned short* NDp = ND + (size_t)ks * T_ * NC_;
    const int r4 = (lane >> 4) * 4;
    const int cc = lane & 15;
#pragma unroll
    for (int fm = 0; fm < 4; fm++)
#pragma unroll
        for (int fn = 0; fn < 4; fn++)
#pragma unroll
            for (int r = 0; r < 4; r++) {
                const int t = t0 + wm * 64 + fm * 16 + r4 + r;
                const int c = c0 + wn * 64 + fn * 16 + cc;
                NDp[(size_t)t * NC_ + c] = f2bf(acc[fm][fn][r]);
            }
}

// ---------------------------------------------------------------------------
// K3: y = sigmoid(Q)*num/den; out[b][t][d] = y @ wp.T + bp.
// grid (T/32, B), block 256.
// ---------------------------------------------------------------------------
__global__ __launch_bounds__(256) void epilogue_kernel(
    const unsigned short* __restrict__ Qb, const unsigned short* __restrict__ ND,
    const float* __restrict__ wp, const float* __restrict__ bp,
    float* __restrict__ out, int write_both)
{
    __shared__ float ysT[64][36];
    __shared__ float wpL[64][132];

    const int tid  = threadIdx.x;
    const int t0   = blockIdx.x * 32;
    const int b    = blockIdx.y;
    const int lane = tid & 63;
    const int trow = tid >> 6;
    const unsigned short* ND1 = ND + (size_t)T_ * NC_;

    for (int pass = 0; pass < 8; pass++) {
        const int t = pass * 4 + trow;
        float q   = bf2f(Qb[((size_t)b * T_ + t0 + t) * H_ + lane]);
        float num = bf2f(ND [(size_t)(t0 + t) * NC_ + b * 64 + lane])
                  + bf2f(ND1[(size_t)(t0 + t) * NC_ + b * 64 + lane]);
        float den = bf2f(ND [(size_t)(t0 + t) * NC_ + 512 + b * 64 + lane])
                  + bf2f(ND1[(size_t)(t0 + t) * NC_ + 512 + b * 64 + lane]);
        float y = (1.f / (1.f + __expf(-q))) * num / den;
        ysT[lane][t] = y;
    }

    const int i = tid >> 5;
    const int j = tid & 31;

    for (int dc = 0; dc < 4; dc++) {
        __syncthreads();
        for (int pass = 0; pass < 8; pass++) {
            const int row = pass * 16 + (tid >> 4);
            const int h4  = (tid & 15) * 4;
            float4 v = *(const float4*)&wp[(size_t)(dc * 128 + row) * H_ + h4];
            wpL[h4 + 0][row] = v.x;
            wpL[h4 + 1][row] = v.y;
            wpL[h4 + 2][row] = v.z;
            wpL[h4 + 3][row] = v.w;
        }
        __syncthreads();

        float acc[4][4] = {};
#pragma unroll
        for (int h = 0; h < 64; h++) {
            float a4[4], b4[4];
            *(float4*)a4 = *(const float4*)&ysT[h][i * 4];
            *(float4*)b4 = *(const float4*)&wpL[h][j * 4];
#pragma unroll
            for (int p = 0; p < 4; p++)
#pragma unroll
                for (int q = 0; q < 4; q++) acc[p][q] += a4[p] * b4[q];
        }
#pragma unroll
        for (int p = 0; p < 4; p++) {
            const int t = t0 + i * 4 + p;
            const int d = dc * 128 + j * 4;
            float4 bpv = *(const float4*)&bp[d];
            float4 v = {acc[p][0] + bpv.x, acc[p][1] + bpv.y,
                        acc[p][2] + bpv.z, acc[p][3] + bpv.w};
            *(float4*)&out[((size_t)b * T_ + t) * DIM_ + d] = v;
            if (write_both)
                *(float4*)&out[(size_t)B_ * T_ * DIM_ + ((size_t)b * T_ + t) * DIM_ + d] = v;
        }
    }
}

__global__ void dup_kernel(const float4* __restrict__ src, float4* __restrict__ dst, int n4)
{
    int idx = blockIdx.x * blockDim.x + threadIdx.x;
    int stride = gridDim.x * blockDim.x;
    for (int k = idx; k < n4; k += stride) dst[k] = src[k];
}

extern "C" void kernel_launch(void* const* d_in, const int* in_sizes, int n_in,
                              void* d_out, int out_size, void* d_ws, size_t ws_size,
                              hipStream_t stream)
{
    const float* x     = (const float*)d_in[0];
    const float* wq    = (const float*)d_in[1];
    const float* bq    = (const float*)d_in[2];
    const float* wk    = (const float*)d_in[3];
    const float* bk    = (const float*)d_in[4];
    const float* wv    = (const float*)d_in[5];
    const float* bv    = (const float*)d_in[6];
    const float* wp    = (const float*)d_in[7];
    const float* bp    = (const float*)d_in[8];
    const float* wbias = (const float*)d_in[9];
    float* out = (float*)d_out;

    const size_t SZ_COPY = (size_t)B_ * T_ * DIM_;   // floats per output copy

    // scratch layout (bytes):
    //   Aexp   bf16 [4096][4096]          33,554,432   @ 0
    //   xT/ND  bf16 chunk / [2][4096][1024] 16,777,216 @ 33,554,432  (aliased)
    //   SbT    bf16 [1024][4096]           8,388,608   @ 50,331,648
    //   Qbuf   bf16 [8][4096][64]          4,194,304   @ 58,720,256
    //   Wcat   bf16 [192][512]               196,608   @ 62,914,560
    //   bcat   f32  [192]                        768   @ 63,111,168
    const size_t NEED = 63111936;
    char* R;
    int write_both;
    if (ws_size >= NEED) {
        R = (char*)d_ws;
        write_both = 1;
    } else {
        R = (char*)(out + SZ_COPY);   // stash in not-yet-written second copy
        write_both = 0;
    }
    unsigned short* Aexp  = (unsigned short*)R;
    unsigned short* xT    = (unsigned short*)(R + 33554432);
    unsigned short* NDbuf = (unsigned short*)(R + 33554432);
    unsigned short* SbT   = (unsigned short*)(R + 50331648);
    unsigned short* Qbuf  = (unsigned short*)(R + 58720256);
    unsigned short* Wcat  = (unsigned short*)(R + 62914560);
    float*          bcat  = (float*)(R + 63111168);

    ewb_kernel<<<2048, 256, 0, stream>>>(wbias, Aexp);
    wcat_kernel<<<192, 128, 0, stream>>>(wq, bq, wk, bk, wv, bv, Wcat, bcat);
    for (int chunk = 0; chunk < 2; chunk++) {
        const int b0 = chunk * 4;
        xpose_kernel<<<dim3(T_ / 64, DIM_ / 64, 4), 256, 0, stream>>>(x, xT, b0);
        qkv_mfma<<<dim3(T_ / 64, 4), 256, 0, stream>>>(xT, Wcat, bcat, Qbuf, SbT, b0);
    }
    aft_gemm_mfma<<<dim3(NC_ / 128, T_ / 128, 2), 256, 0, stream>>>(Aexp, SbT, NDbuf);
    epilogue_kernel<<<dim3(T_ / 32, B_), 256, 0, stream>>>(Qbuf, NDbuf, wp, bp, out, write_both);
    if (!write_both)
        dup_kernel<<<2048, 256, 0, stream>>>((const float4*)out,
                                             (float4*)(out + SZ_COPY),
                                             (int)(SZ_COPY / 4));
}

// Round 4
// 182.551 us; speedup vs baseline: 3.6233x; 1.1666x over previous
//
#include <hip/hip_runtime.h>
#include <hip/hip_bf16.h>

#define B_   8
#define DIM_ 512
#define T_   4096
#define H_   64
#define NC_  1024   // 2*B*H : cols 0..511 = eK*V (c=b*64+h), 512..1023 = eK

typedef __attribute__((ext_vector_type(8))) short short8;
typedef __attribute__((ext_vector_type(4))) float f32x4;

__device__ __forceinline__ unsigned short f2bf(float x) {
    __hip_bfloat16 h = __float2bfloat16(x);
    return *reinterpret_cast<unsigned short*>(&h);
}
__device__ __forceinline__ float bf2f(unsigned short u) {
    __hip_bfloat16 h = *reinterpret_cast<__hip_bfloat16*>(&u);
    return __bfloat162float(h);
}
__device__ __forceinline__ void gload16(const void* g, void* l) {
    __builtin_amdgcn_global_load_lds(
        (const __attribute__((address_space(1))) unsigned int*)g,
        (__attribute__((address_space(3))) unsigned int*)l, 16, 0, 0);
}

// ---------------------------------------------------------------------------
// K0: Aexp[t][s] = bf16(exp(wbias[t][s]))
// ---------------------------------------------------------------------------
__global__ __launch_bounds__(256) void ewb_kernel(
    const float* __restrict__ wb, unsigned short* __restrict__ Aexp)
{
    const int n4 = T_ * T_ / 4;
    int idx = blockIdx.x * blockDim.x + threadIdx.x;
    int stride = gridDim.x * blockDim.x;
    for (int i = idx; i < n4; i += stride) {
        float4 v = ((const float4*)wb)[i];
        ushort4 o;
        o.x = f2bf(__expf(v.x));
        o.y = f2bf(__expf(v.y));
        o.z = f2bf(__expf(v.z));
        o.w = f2bf(__expf(v.w));
        ((ushort4*)Aexp)[i] = o;
    }
}

// ---------------------------------------------------------------------------
// K0b: Wcat[192][512] bf16 from {wq,wk,wv}; bcat[192] f32 from {bq,bk,bv}.
// ---------------------------------------------------------------------------
__global__ __launch_bounds__(128) void wcat_kernel(
    const float* __restrict__ wq, const float* __restrict__ bq,
    const float* __restrict__ wk, const float* __restrict__ bk,
    const float* __restrict__ wv, const float* __restrict__ bv,
    unsigned short* __restrict__ Wcat, float* __restrict__ bcat)
{
    const int r = blockIdx.x;
    const int tid = threadIdx.x;
    const float* src = (r < 64) ? (wq + (size_t)r * DIM_)
                     : (r < 128) ? (wk + (size_t)(r - 64) * DIM_)
                                 : (wv + (size_t)(r - 128) * DIM_);
    const int d4 = tid * 4;
    float4 v = *(const float4*)&src[d4];
    ushort4 o;
    o.x = f2bf(v.x); o.y = f2bf(v.y); o.z = f2bf(v.z); o.w = f2bf(v.w);
    *(ushort4*)&Wcat[(size_t)r * DIM_ + d4] = o;
    if (tid == 0)
        bcat[r] = (r < 64) ? bq[r] : (r < 128) ? bk[r - 64] : bv[r - 128];
}

// ---------------------------------------------------------------------------
// K0c: wpb[512][64] bf16 from wp (row-major, plain layout).
// grid 32, block 256, 4 elems/thread.
// ---------------------------------------------------------------------------
__global__ __launch_bounds__(256) void wpb_kernel(
    const float* __restrict__ wp, unsigned short* __restrict__ wpb)
{
    const int i = (blockIdx.x * 256 + threadIdx.x) * 4;
    float4 v = *(const float4*)&wp[i];
    ushort4 o;
    o.x = f2bf(v.x); o.y = f2bf(v.y); o.z = f2bf(v.z); o.w = f2bf(v.w);
    *(ushort4*)&wpb[i] = o;
}

// ---------------------------------------------------------------------------
// K1a: transpose one 4-batch chunk of x: [4][512][4096] f32 -> xT [4][4096][512] bf16
// ---------------------------------------------------------------------------
__global__ __launch_bounds__(256) void xpose_kernel(
    const float* __restrict__ x, unsigned short* __restrict__ xT, int b0)
{
    __shared__ float st[64 * 65];
    const int tid = threadIdx.x;
    const int t0 = blockIdx.x * 64;
    const int d0 = blockIdx.y * 64;
    const int bl = blockIdx.z;
    const int b  = b0 + bl;

#pragma unroll
    for (int p = 0; p < 4; p++) {
        const int d  = p * 16 + (tid >> 4);
        const int t4 = (tid & 15) * 4;
        float4 v = *(const float4*)&x[((size_t)b * DIM_ + d0 + d) * T_ + t0 + t4];
        *(float4*)&st[d * 65 + t4] = v;
    }
    __syncthreads();
#pragma unroll
    for (int p = 0; p < 2; p++) {
        const int t  = p * 32 + (tid >> 3);
        const int d8 = (tid & 7) * 8;
        union { ushort u[8]; uint4 v; } pk;
#pragma unroll
        for (int jj = 0; jj < 8; jj++)
            pk.u[jj] = f2bf(st[(d8 + jj) * 65 + t]);
        *(uint4*)&xT[((size_t)bl * T_ + t0 + t) * DIM_ + d0 + d8] = pk.v;
    }
}

// ---------------------------------------------------------------------------
// K1b: QKV via MFMA.  grid (T/64, 4), block 256.
// ---------------------------------------------------------------------------
__global__ __launch_bounds__(256) void qkv_mfma(
    const unsigned short* __restrict__ xT, const unsigned short* __restrict__ Wcat,
    const float* __restrict__ bcat,
    unsigned short* __restrict__ Qb, unsigned short* __restrict__ SbT, int b0)
{
    __shared__ unsigned short As[64 * 64];    // [t'][d]
    __shared__ unsigned short Bs[192 * 64];   // [h'][d]

    const int tid = threadIdx.x;
    const int t0 = blockIdx.x * 64;
    const int bl = blockIdx.y;
    const int b  = b0 + bl;
    const int wid = tid >> 6, lane = tid & 63;

    f32x4 acc[12];
    const f32x4 vzero = {0.f, 0.f, 0.f, 0.f};
#pragma unroll
    for (int f = 0; f < 12; f++) acc[f] = vzero;

    const int rs  = tid >> 3;
    const int ks8 = (tid & 7) * 8;
    const unsigned short* Ag = xT + ((size_t)bl * T_ + t0 + rs) * DIM_ + ks8;
    const unsigned short* Bg = Wcat + (size_t)rs * DIM_ + ks8;

    for (int d0 = 0; d0 < DIM_; d0 += 64) {
#pragma unroll
        for (int it = 0; it < 2; it++)
            gload16(Ag + (size_t)(it * 32) * DIM_ + d0, (void*)&As[(it * 256 + tid) * 8]);
#pragma unroll
        for (int it = 0; it < 6; it++)
            gload16(Bg + (size_t)(it * 32) * DIM_ + d0, (void*)&Bs[(it * 256 + tid) * 8]);
        __syncthreads();
        const int row_a = wid * 16 + (lane & 15);
#pragma unroll
        for (int kk = 0; kk < 2; kk++) {
            const int kr = kk * 32 + (lane >> 4) * 8;
            short8 af = *(const short8*)&As[row_a * 64 + kr];
#pragma unroll
            for (int fn = 0; fn < 12; fn++) {
                short8 bf = *(const short8*)&Bs[(fn * 16 + (lane & 15)) * 64 + kr];
                acc[fn] = __builtin_amdgcn_mfma_f32_16x16x32_bf16(af, bf, acc[fn], 0, 0, 0);
            }
        }
        __syncthreads();
    }

    const int cc = lane & 15;
    const int t_base = t0 + wid * 16 + (lane >> 4) * 4;

#pragma unroll
    for (int fn = 0; fn < 4; fn++) {
        const int h = fn * 16 + cc;
        const float bb = bcat[h];
#pragma unroll
        for (int r = 0; r < 4; r++)
            Qb[((size_t)b * T_ + t_base + r) * H_ + h] = f2bf(acc[fn][r] + bb);
    }
#pragma unroll
    for (int f = 0; f < 4; f++) {
        const int h = f * 16 + cc;
        const float bK = bcat[64 + h];
        const float bV = bcat[128 + h];
        ushort4 pk, pe;
        float e0 = __expf(acc[4 + f][0] + bK), v0 = acc[8 + f][0] + bV;
        float e1 = __expf(acc[4 + f][1] + bK), v1 = acc[8 + f][1] + bV;
        float e2 = __expf(acc[4 + f][2] + bK), v2 = acc[8 + f][2] + bV;
        float e3 = __expf(acc[4 + f][3] + bK), v3 = acc[8 + f][3] + bV;
        pe.x = f2bf(e0); pe.y = f2bf(e1); pe.z = f2bf(e2); pe.w = f2bf(e3);
        pk.x = f2bf(e0 * v0); pk.y = f2bf(e1 * v1); pk.z = f2bf(e2 * v2); pk.w = f2bf(e3 * v3);
        *(ushort4*)&SbT[(size_t)(b * 64 + h) * T_ + t_base] = pk;
        *(ushort4*)&SbT[(size_t)(512 + b * 64 + h) * T_ + t_base] = pe;
    }
}

// ---------------------------------------------------------------------------
// K2: ND[ks][t][c] = sum_{s in half ks} Aexp[t][s] * SbT[c][s]   (bf16 MFMA)
// ---------------------------------------------------------------------------
__global__ __launch_bounds__(256) void aft_gemm_mfma(
    const unsigned short* __restrict__ Aexp,
    const unsigned short* __restrict__ SbT,
    unsigned short* __restrict__ ND)
{
    __shared__ unsigned short As[128 * 64];   // [t'][k]
    __shared__ unsigned short Bs[128 * 64];   // [c'][k]

    const int tid = threadIdx.x;
    const int c0 = blockIdx.x * 128;
    const int t0 = blockIdx.y * 128;
    const int ks = blockIdx.z;
    const int sbase = ks * (T_ / 2);

    const int wid = tid >> 6, lane = tid & 63;
    const int wm = wid >> 1, wn = wid & 1;

    f32x4 acc[4][4];
    const f32x4 vzero = {0.f, 0.f, 0.f, 0.f};
#pragma unroll
    for (int a = 0; a < 4; a++)
#pragma unroll
        for (int b2 = 0; b2 < 4; b2++) acc[a][b2] = vzero;

    const int rs  = tid >> 3;
    const int ks8 = (tid & 7) * 8;
    const unsigned short* Ag = Aexp + (size_t)(t0 + rs) * T_ + sbase + ks8;
    const unsigned short* Bg = SbT  + (size_t)(c0 + rs) * T_ + sbase + ks8;

    for (int s0 = 0; s0 < T_ / 2; s0 += 64) {
#pragma unroll
        for (int it = 0; it < 4; it++) {
            gload16(Ag + (size_t)(it * 32) * T_ + s0, (void*)&As[(it * 256 + tid) * 8]);
            gload16(Bg + (size_t)(it * 32) * T_ + s0, (void*)&Bs[(it * 256 + tid) * 8]);
        }
        __syncthreads();
        const int row_a = wm * 64 + (lane & 15);
        const int row_b = wn * 64 + (lane & 15);
#pragma unroll
        for (int kk = 0; kk < 2; kk++) {
            const int kr = kk * 32 + (lane >> 4) * 8;
            short8 af[4], bfr[4];
#pragma unroll
            for (int f = 0; f < 4; f++)
                af[f] = *(const short8*)&As[(row_a + f * 16) * 64 + kr];
#pragma unroll
            for (int f = 0; f < 4; f++)
                bfr[f] = *(const short8*)&Bs[(row_b + f * 16) * 64 + kr];
#pragma unroll
            for (int fm = 0; fm < 4; fm++)
#pragma unroll
                for (int fn = 0; fn < 4; fn++)
                    acc[fm][fn] = __builtin_amdgcn_mfma_f32_16x16x32_bf16(
                        af[fm], bfr[fn], acc[fm][fn], 0, 0, 0);
        }
        __syncthreads();
    }

    unsigned short* NDp = ND + (size_t)ks * T_ * NC_;
    const int r4 = (lane >> 4) * 4;
    const int cc = lane & 15;
#pragma unroll
    for (int fm = 0; fm < 4; fm++)
#pragma unroll
        for (int fn = 0; fn < 4; fn++)
#pragma unroll
            for (int r = 0; r < 4; r++) {
                const int t = t0 + wm * 64 + fm * 16 + r4 + r;
                const int c = c0 + wn * 64 + fn * 16 + cc;
                NDp[(size_t)t * NC_ + c] = f2bf(acc[fm][fn][r]);
            }
}

// ---------------------------------------------------------------------------
// K3: epilogue via MFMA.  grid (T/64, B), block 256 (4 waves).
// y[t][h] = sigmoid(Q)*num/den (bf16, XOR-swizzled LDS);
// out[b][t][d] = y @ wpb.T + bp, K=64, M-tile 64, N=512 full.
// C written through LDS bounce for coalesced float4 stores (both copies).
// ---------------------------------------------------------------------------
__global__ __launch_bounds__(256) void epilogue_mfma(
    const unsigned short* __restrict__ Qb, const unsigned short* __restrict__ ND,
    const unsigned short* __restrict__ wpb, const float* __restrict__ bp,
    float* __restrict__ out, int write_both)
{
    __shared__ unsigned short y_s[64 * 64];    // 8 KB, swizzled [t][h]
    __shared__ unsigned short wp_s[512 * 64];  // 64 KB, swizzled [d][h]; reused as bounce
    float* st = (float*)wp_s;                  // bounce: [64][68] f32 (17.4 KB)

    const int tid  = threadIdx.x;
    const int t0   = blockIdx.x * 64;
    const int b    = blockIdx.y;
    const int wid  = tid >> 6, lane = tid & 63;
    const size_t SZ_COPY = (size_t)B_ * T_ * DIM_;

    // --- stage wpb -> wp_s: linear LDS dest, pre-swizzled global source ---
    {
        const int rs = tid >> 3;      // 0..31
        const int c8 = tid & 7;
#pragma unroll
        for (int p = 0; p < 16; p++) {
            const int row = p * 32 + rs;
            gload16(wpb + (size_t)row * 64 + ((c8 ^ (row & 7)) << 3),
                    (void*)&wp_s[((size_t)row * 8 + c8) * 8]);
        }
    }
    // --- compute y -> y_s (swizzled ds_write), overlaps with async staging ---
    {
        const int t   = tid >> 2;
        const int h16 = (tid & 3) * 16;
        const unsigned short* ND1 = ND + (size_t)T_ * NC_;
        const size_t qoff = ((size_t)b * T_ + t0 + t) * H_ + h16;
        const size_t noff = (size_t)(t0 + t) * NC_ + b * 64 + h16;
        float yv[16];
#pragma unroll
        for (int u = 0; u < 16; u++) {
            float q   = bf2f(Qb[qoff + u]);
            float num = bf2f(ND[noff + u]) + bf2f(ND1[noff + u]);
            float den = bf2f(ND[noff + 512 + u]) + bf2f(ND1[noff + 512 + u]);
            yv[u] = (1.f / (1.f + __expf(-q))) * num / den;
        }
#pragma unroll
        for (int u = 0; u < 2; u++) {
            const int h8 = (tid & 3) * 2 + u;
            union { unsigned short s[8]; short8 v; } pk;
#pragma unroll
            for (int e = 0; e < 8; e++) pk.s[e] = f2bf(yv[u * 8 + e]);
            *(short8*)((char*)y_s + t * 128 + ((h8 ^ (t & 7)) << 4)) = pk.v;
        }
    }
    __syncthreads();

    // --- MFMA: rows = t0 + wid*16 + (lane&15); 32 n-frags cover d 0..511 ---
    f32x4 acc[32];
    const f32x4 vzero = {0.f, 0.f, 0.f, 0.f};
#pragma unroll
    for (int f = 0; f < 32; f++) acc[f] = vzero;

    const int ra = wid * 16 + (lane & 15);
    short8 af[2];
#pragma unroll
    for (int kk = 0; kk < 2; kk++)
        af[kk] = *(const short8*)((char*)y_s + ra * 128 +
                                  (((kk * 4 + (lane >> 4)) ^ (ra & 7)) << 4));
#pragma unroll
    for (int fn = 0; fn < 32; fn++) {
        const int rb = fn * 16 + (lane & 15);
#pragma unroll
        for (int kk = 0; kk < 2; kk++) {
            short8 bf = *(const short8*)((char*)wp_s + rb * 128 +
                                         (((kk * 4 + (lane >> 4)) ^ (rb & 7)) << 4));
            acc[fn] = __builtin_amdgcn_mfma_f32_16x16x32_bf16(af[kk], bf, acc[fn], 0, 0, 0);
        }
    }

    // --- bounce + coalesced writes, 8 chunks of 64 d ---
    const int cc = lane & 15;
    const int rg = lane >> 4;
#pragma unroll
    for (int ch = 0; ch < 8; ch++) {
        __syncthreads();   // chunk's LDS region free (first iter: wp_s fully consumed)
#pragma unroll
        for (int f = 0; f < 4; f++) {
#pragma unroll
            for (int r = 0; r < 4; r++)
                st[(wid * 16 + rg * 4 + r) * 68 + f * 16 + cc] = acc[ch * 4 + f][r];
        }
        __syncthreads();
        const int row   = tid >> 2;
        const int dq    = (tid & 3) * 16;
        const int dbase = ch * 64 + dq;
        const size_t obase = ((size_t)b * T_ + t0 + row) * DIM_ + dbase;
#pragma unroll
        for (int i = 0; i < 4; i++) {
            float4 v  = *(const float4*)&st[row * 68 + dq + i * 4];
            float4 bb = *(const float4*)&bp[dbase + i * 4];
            float4 o  = {v.x + bb.x, v.y + bb.y, v.z + bb.z, v.w + bb.w};
            *(float4*)&out[obase + i * 4] = o;
            if (write_both)
                *(float4*)&out[SZ_COPY + obase + i * 4] = o;
        }
    }
}

__global__ void dup_kernel(const float4* __restrict__ src, float4* __restrict__ dst, int n4)
{
    int idx = blockIdx.x * blockDim.x + threadIdx.x;
    int stride = gridDim.x * blockDim.x;
    for (int k = idx; k < n4; k += stride) dst[k] = src[k];
}

extern "C" void kernel_launch(void* const* d_in, const int* in_sizes, int n_in,
                              void* d_out, int out_size, void* d_ws, size_t ws_size,
                              hipStream_t stream)
{
    const float* x     = (const float*)d_in[0];
    const float* wq    = (const float*)d_in[1];
    const float* bq    = (const float*)d_in[2];
    const float* wk    = (const float*)d_in[3];
    const float* bk    = (const float*)d_in[4];
    const float* wv    = (const float*)d_in[5];
    const float* bv    = (const float*)d_in[6];
    const float* wp    = (const float*)d_in[7];
    const float* bp    = (const float*)d_in[8];
    const float* wbias = (const float*)d_in[9];
    float* out = (float*)d_out;

    const size_t SZ_COPY = (size_t)B_ * T_ * DIM_;

    // scratch layout (bytes):
    //   Aexp   bf16 [4096][4096]            33,554,432 @ 0
    //   xT/ND  bf16 chunk / [2][4096][1024] 16,777,216 @ 33,554,432 (aliased)
    //   SbT    bf16 [1024][4096]             8,388,608 @ 50,331,648
    //   Qbuf   bf16 [8][4096][64]            4,194,304 @ 58,720,256
    //   Wcat   bf16 [192][512]                 196,608 @ 62,914,560
    //   wpb    bf16 [512][64]                   65,536 @ 63,111,168
    //   bcat   f32  [192]                          768 @ 63,176,704
    const size_t NEED = 63177472;
    char* R;
    int write_both;
    if (ws_size >= NEED) {
        R = (char*)d_ws;
        write_both = 1;
    } else {
        R = (char*)(out + SZ_COPY);
        write_both = 0;
    }
    unsigned short* Aexp  = (unsigned short*)R;
    unsigned short* xT    = (unsigned short*)(R + 33554432);
    unsigned short* NDbuf = (unsigned short*)(R + 33554432);
    unsigned short* SbT   = (unsigned short*)(R + 50331648);
    unsigned short* Qbuf  = (unsigned short*)(R + 58720256);
    unsigned short* Wcat  = (unsigned short*)(R + 62914560);
    unsigned short* wpb   = (unsigned short*)(R + 63111168);
    float*          bcat  = (float*)(R + 63176704);

    ewb_kernel<<<2048, 256, 0, stream>>>(wbias, Aexp);
    wcat_kernel<<<192, 128, 0, stream>>>(wq, bq, wk, bk, wv, bv, Wcat, bcat);
    wpb_kernel<<<32, 256, 0, stream>>>(wp, wpb);
    for (int chunk = 0; chunk < 2; chunk++) {
        const int b0 = chunk * 4;
        xpose_kernel<<<dim3(T_ / 64, DIM_ / 64, 4), 256, 0, stream>>>(x, xT, b0);
        qkv_mfma<<<dim3(T_ / 64, 4), 256, 0, stream>>>(xT, Wcat, bcat, Qbuf, SbT, b0);
    }
    aft_gemm_mfma<<<dim3(NC_ / 128, T_ / 128, 2), 256, 0, stream>>>(Aexp, SbT, NDbuf);
    epilogue_mfma<<<dim3(T_ / 64, B_), 256, 0, stream>>>(Qbuf, NDbuf, wpb, bp, out, write_both);
    if (!write_both)
        dup_kernel<<<2048, 256, 0, stream>>>((const float4*)out,
                                             (float4*)(out + SZ_COPY),
                                             (int)(SZ_COPY / 4));
}

// Round 6
// 163.207 us; speedup vs baseline: 4.0528x; 1.1185x over previous
//
#include <hip/hip_runtime.h>
#include <hip/hip_bf16.h>

#define B_   8
#define DIM_ 512
#define T_   4096
#define H_   64
#define NC_  1024   // 2*B*H : cols 0..511 = eK*V (c=b*64+h), 512..1023 = eK

typedef __attribute__((ext_vector_type(8))) short short8;
typedef __attribute__((ext_vector_type(4))) float f32x4;

__device__ __forceinline__ unsigned short f2bf(float x) {
    __hip_bfloat16 h = __float2bfloat16(x);
    return *reinterpret_cast<unsigned short*>(&h);
}
__device__ __forceinline__ float bf2f(unsigned short u) {
    __hip_bfloat16 h = *reinterpret_cast<__hip_bfloat16*>(&u);
    return __bfloat162float(h);
}
__device__ __forceinline__ void gload16(const void* g, void* l) {
    __builtin_amdgcn_global_load_lds(
        (const __attribute__((address_space(1))) unsigned int*)g,
        (__attribute__((address_space(3))) unsigned int*)l, 16, 0, 0);
}

// ---------------------------------------------------------------------------
// K0: Aexp[t][s] = bf16(exp(wbias[t][s]))
// ---------------------------------------------------------------------------
__global__ __launch_bounds__(256) void ewb_kernel(
    const float* __restrict__ wb, unsigned short* __restrict__ Aexp)
{
    const int n4 = T_ * T_ / 4;
    int idx = blockIdx.x * blockDim.x + threadIdx.x;
    int stride = gridDim.x * blockDim.x;
    for (int i = idx; i < n4; i += stride) {
        float4 v = ((const float4*)wb)[i];
        ushort4 o;
        o.x = f2bf(__expf(v.x));
        o.y = f2bf(__expf(v.y));
        o.z = f2bf(__expf(v.z));
        o.w = f2bf(__expf(v.w));
        ((ushort4*)Aexp)[i] = o;
    }
}

// ---------------------------------------------------------------------------
// K0b: Wcat[192][512] bf16 from {wq,wk,wv}; bcat[192] f32 from {bq,bk,bv}.
// ---------------------------------------------------------------------------
__global__ __launch_bounds__(128) void wcat_kernel(
    const float* __restrict__ wq, const float* __restrict__ bq,
    const float* __restrict__ wk, const float* __restrict__ bk,
    const float* __restrict__ wv, const float* __restrict__ bv,
    unsigned short* __restrict__ Wcat, float* __restrict__ bcat)
{
    const int r = blockIdx.x;
    const int tid = threadIdx.x;
    const float* src = (r < 64) ? (wq + (size_t)r * DIM_)
                     : (r < 128) ? (wk + (size_t)(r - 64) * DIM_)
                                 : (wv + (size_t)(r - 128) * DIM_);
    const int d4 = tid * 4;
    float4 v = *(const float4*)&src[d4];
    ushort4 o;
    o.x = f2bf(v.x); o.y = f2bf(v.y); o.z = f2bf(v.z); o.w = f2bf(v.w);
    *(ushort4*)&Wcat[(size_t)r * DIM_ + d4] = o;
    if (tid == 0)
        bcat[r] = (r < 64) ? bq[r] : (r < 128) ? bk[r - 64] : bv[r - 128];
}

// ---------------------------------------------------------------------------
// K0c: wpb[512][64] bf16 from wp.
// ---------------------------------------------------------------------------
__global__ __launch_bounds__(256) void wpb_kernel(
    const float* __restrict__ wp, unsigned short* __restrict__ wpb)
{
    const int i = (blockIdx.x * 256 + threadIdx.x) * 4;
    float4 v = *(const float4*)&wp[i];
    ushort4 o;
    o.x = f2bf(v.x); o.y = f2bf(v.y); o.z = f2bf(v.z); o.w = f2bf(v.w);
    *(ushort4*)&wpb[i] = o;
}

// ---------------------------------------------------------------------------
// K1a: transpose one 4-batch chunk of x: [4][512][4096] f32 -> xT [4][4096][512] bf16
// ---------------------------------------------------------------------------
__global__ __launch_bounds__(256) void xpose_kernel(
    const float* __restrict__ x, unsigned short* __restrict__ xT, int b0)
{
    __shared__ float st[64 * 65];
    const int tid = threadIdx.x;
    const int t0 = blockIdx.x * 64;
    const int d0 = blockIdx.y * 64;
    const int bl = blockIdx.z;
    const int b  = b0 + bl;

#pragma unroll
    for (int p = 0; p < 4; p++) {
        const int d  = p * 16 + (tid >> 4);
        const int t4 = (tid & 15) * 4;
        float4 v = *(const float4*)&x[((size_t)b * DIM_ + d0 + d) * T_ + t0 + t4];
        *(float4*)&st[d * 65 + t4] = v;
    }
    __syncthreads();
#pragma unroll
    for (int p = 0; p < 2; p++) {
        const int t  = p * 32 + (tid >> 3);
        const int d8 = (tid & 7) * 8;
        union { ushort u[8]; uint4 v; } pk;
#pragma unroll
        for (int jj = 0; jj < 8; jj++)
            pk.u[jj] = f2bf(st[(d8 + jj) * 65 + t]);
        *(uint4*)&xT[((size_t)bl * T_ + t0 + t) * DIM_ + d0 + d8] = pk.v;
    }
}

// ---------------------------------------------------------------------------
// K1b: QKV via MFMA.  grid (T/64, 4), block 256.
// ---------------------------------------------------------------------------
__global__ __launch_bounds__(256) void qkv_mfma(
    const unsigned short* __restrict__ xT, const unsigned short* __restrict__ Wcat,
    const float* __restrict__ bcat,
    unsigned short* __restrict__ Qb, unsigned short* __restrict__ SbT, int b0)
{
    __shared__ unsigned short As[64 * 64];    // [t'][d]
    __shared__ unsigned short Bs[192 * 64];   // [h'][d]

    const int tid = threadIdx.x;
    const int t0 = blockIdx.x * 64;
    const int bl = blockIdx.y;
    const int b  = b0 + bl;
    const int wid = tid >> 6, lane = tid & 63;

    f32x4 acc[12];
    const f32x4 vzero = {0.f, 0.f, 0.f, 0.f};
#pragma unroll
    for (int f = 0; f < 12; f++) acc[f] = vzero;

    const int rs  = tid >> 3;
    const int ks8 = (tid & 7) * 8;
    const unsigned short* Ag = xT + ((size_t)bl * T_ + t0 + rs) * DIM_ + ks8;
    const unsigned short* Bg = Wcat + (size_t)rs * DIM_ + ks8;

    for (int d0 = 0; d0 < DIM_; d0 += 64) {
#pragma unroll
        for (int it = 0; it < 2; it++)
            gload16(Ag + (size_t)(it * 32) * DIM_ + d0, (void*)&As[(it * 256 + tid) * 8]);
#pragma unroll
        for (int it = 0; it < 6; it++)
            gload16(Bg + (size_t)(it * 32) * DIM_ + d0, (void*)&Bs[(it * 256 + tid) * 8]);
        __syncthreads();
        const int row_a = wid * 16 + (lane & 15);
#pragma unroll
        for (int kk = 0; kk < 2; kk++) {
            const int kr = kk * 32 + (lane >> 4) * 8;
            short8 af = *(const short8*)&As[row_a * 64 + kr];
#pragma unroll
            for (int fn = 0; fn < 12; fn++) {
                short8 bf = *(const short8*)&Bs[(fn * 16 + (lane & 15)) * 64 + kr];
                acc[fn] = __builtin_amdgcn_mfma_f32_16x16x32_bf16(af, bf, acc[fn], 0, 0, 0);
            }
        }
        __syncthreads();
    }

    const int cc = lane & 15;
    const int t_base = t0 + wid * 16 + (lane >> 4) * 4;

#pragma unroll
    for (int fn = 0; fn < 4; fn++) {
        const int h = fn * 16 + cc;
        const float bb = bcat[h];
#pragma unroll
        for (int r = 0; r < 4; r++)
            Qb[((size_t)b * T_ + t_base + r) * H_ + h] = f2bf(acc[fn][r] + bb);
    }
#pragma unroll
    for (int f = 0; f < 4; f++) {
        const int h = f * 16 + cc;
        const float bK = bcat[64 + h];
        const float bV = bcat[128 + h];
        ushort4 pk, pe;
        float e0 = __expf(acc[4 + f][0] + bK), v0 = acc[8 + f][0] + bV;
        float e1 = __expf(acc[4 + f][1] + bK), v1 = acc[8 + f][1] + bV;
        float e2 = __expf(acc[4 + f][2] + bK), v2 = acc[8 + f][2] + bV;
        float e3 = __expf(acc[4 + f][3] + bK), v3 = acc[8 + f][3] + bV;
        pe.x = f2bf(e0); pe.y = f2bf(e1); pe.z = f2bf(e2); pe.w = f2bf(e3);
        pk.x = f2bf(e0 * v0); pk.y = f2bf(e1 * v1); pk.z = f2bf(e2 * v2); pk.w = f2bf(e3 * v3);
        *(ushort4*)&SbT[(size_t)(b * 64 + h) * T_ + t_base] = pk;
        *(ushort4*)&SbT[(size_t)(512 + b * 64 + h) * T_ + t_base] = pe;
    }
}

// ---------------------------------------------------------------------------
// K2: ND[ks][t][c] = sum_{s in half ks} Aexp[t][s] * SbT[c][s]   (bf16 MFMA)
// 128x128 tile, BK=64, split-K=2.  XCD-aware bijective swizzle (512 blocks,
// 512%8==0): each XCD gets 8 contiguous t-panels of one K-half (A ~4MB = L2).
// ---------------------------------------------------------------------------
__global__ __launch_bounds__(256) void aft_gemm_mfma(
    const unsigned short* __restrict__ Aexp,
    const unsigned short* __restrict__ SbT,
    unsigned short* __restrict__ ND)
{
    __shared__ unsigned short As[128 * 64];   // [t'][k]
    __shared__ unsigned short Bs[128 * 64];   // [c'][k]

    const int tid = threadIdx.x;
    const int lin = blockIdx.x + (blockIdx.y << 3) + (blockIdx.z << 8); // 0..511
    const int swz = ((lin & 7) << 6) + (lin >> 3);                      // bijective
    const int c0 = (swz & 7) * 128;
    const int t0 = ((swz >> 3) & 31) * 128;
    const int ks = swz >> 8;
    const int sbase = ks * (T_ / 2);

    const int wid = tid >> 6, lane = tid & 63;
    const int wm = wid >> 1, wn = wid & 1;

    f32x4 acc[4][4];
    const f32x4 vzero = {0.f, 0.f, 0.f, 0.f};
#pragma unroll
    for (int a = 0; a < 4; a++)
#pragma unroll
        for (int b2 = 0; b2 < 4; b2++) acc[a][b2] = vzero;

    const int rs  = tid >> 3;
    const int ks8 = (tid & 7) * 8;
    const unsigned short* Ag = Aexp + (size_t)(t0 + rs) * T_ + sbase + ks8;
    const unsigned short* Bg = SbT  + (size_t)(c0 + rs) * T_ + sbase + ks8;

    for (int s0 = 0; s0 < T_ / 2; s0 += 64) {
#pragma unroll
        for (int it = 0; it < 4; it++) {
            gload16(Ag + (size_t)(it * 32) * T_ + s0, (void*)&As[(it * 256 + tid) * 8]);
            gload16(Bg + (size_t)(it * 32) * T_ + s0, (void*)&Bs[(it * 256 + tid) * 8]);
        }
        __syncthreads();
        const int row_a = wm * 64 + (lane & 15);
        const int row_b = wn * 64 + (lane & 15);
#pragma unroll
        for (int kk = 0; kk < 2; kk++) {
            const int kr = kk * 32 + (lane >> 4) * 8;
            short8 af[4], bfr[4];
#pragma unroll
            for (int f = 0; f < 4; f++)
                af[f] = *(const short8*)&As[(row_a + f * 16) * 64 + kr];
#pragma unroll
            for (int f = 0; f < 4; f++)
                bfr[f] = *(const short8*)&Bs[(row_b + f * 16) * 64 + kr];
#pragma unroll
            for (int fm = 0; fm < 4; fm++)
#pragma unroll
                for (int fn = 0; fn < 4; fn++)
                    acc[fm][fn] = __builtin_amdgcn_mfma_f32_16x16x32_bf16(
                        af[fm], bfr[fn], acc[fm][fn], 0, 0, 0);
        }
        __syncthreads();
    }

    unsigned short* NDp = ND + (size_t)ks * T_ * NC_;
    const int r4 = (lane >> 4) * 4;
    const int cc = lane & 15;
#pragma unroll
    for (int fm = 0; fm < 4; fm++)
#pragma unroll
        for (int fn = 0; fn < 4; fn++)
#pragma unroll
            for (int r = 0; r < 4; r++) {
                const int t = t0 + wm * 64 + fm * 16 + r4 + r;
                const int c = c0 + wn * 64 + fn * 16 + cc;
                NDp[(size_t)t * NC_ + c] = f2bf(acc[fm][fn][r]);
            }
}

// ---------------------------------------------------------------------------
// K3: epilogue via MFMA.  grid (T/64, B), block 256 (4 waves).
// y = sigmoid(Q)*num/den (bf16, XOR-swizzled LDS); out = y @ wpb.T + bp.
// C-write: cooperative 2-chunk bounce (d-halves), LDS [64][260] f32,
// barrier-ordered (4 barriers total), fully-contiguous 1KB stores/instr.
// ---------------------------------------------------------------------------
__global__ __launch_bounds__(256) void epilogue_mfma(
    const unsigned short* __restrict__ Qb, const unsigned short* __restrict__ ND,
    const unsigned short* __restrict__ wpb, const float* __restrict__ bp,
    float* __restrict__ out, int write_both)
{
    __shared__ unsigned short smem[36864];      // 72 KB
    unsigned short* y_s  = smem;                // 8 KB, swizzled [t][h]
    unsigned short* wp_s = smem + 4096;         // 64 KB, swizzled [d][h]
    float* st = (float*)smem;                   // bounce [64][260] f32 (66.6 KB)

    const int tid  = threadIdx.x;
    const int t0   = blockIdx.x * 64;
    const int b    = blockIdx.y;
    const int wid  = tid >> 6, lane = tid & 63;
    const size_t SZ_COPY = (size_t)B_ * T_ * DIM_;

    // --- stage wpb -> wp_s: linear LDS dest, pre-swizzled global source ---
    {
        const int rs = tid >> 3;      // 0..31
        const int c8 = tid & 7;
#pragma unroll
        for (int p = 0; p < 16; p++) {
            const int row = p * 32 + rs;
            gload16(wpb + (size_t)row * 64 + ((c8 ^ (row & 7)) << 3),
                    (void*)&wp_s[((size_t)row * 8 + c8) * 8]);
        }
    }
    // --- compute y -> y_s (swizzled ds_write), overlaps with async staging ---
    {
        const int t   = tid >> 2;
        const int h16 = (tid & 3) * 16;
        const unsigned short* ND1 = ND + (size_t)T_ * NC_;
        const size_t qoff = ((size_t)b * T_ + t0 + t) * H_ + h16;
        const size_t noff = (size_t)(t0 + t) * NC_ + b * 64 + h16;
        float yv[16];
#pragma unroll
        for (int u = 0; u < 16; u++) {
            float q   = bf2f(Qb[qoff + u]);
            float num = bf2f(ND[noff + u]) + bf2f(ND1[noff + u]);
            float den = bf2f(ND[noff + 512 + u]) + bf2f(ND1[noff + 512 + u]);
            yv[u] = (1.f / (1.f + __expf(-q))) * num / den;
        }
#pragma unroll
        for (int u = 0; u < 2; u++) {
            const int h8 = (tid & 3) * 2 + u;
            union { unsigned short s[8]; short8 v; } pk;
#pragma unroll
            for (int e = 0; e < 8; e++) pk.s[e] = f2bf(yv[u * 8 + e]);
            *(short8*)((char*)y_s + t * 128 + ((h8 ^ (t & 7)) << 4)) = pk.v;
        }
    }
    __syncthreads();

    // --- MFMA: rows = t0 + wid*16 + (lane&15); 32 n-frags cover d 0..511 ---
    f32x4 acc[32];
    const f32x4 vzero = {0.f, 0.f, 0.f, 0.f};
#pragma unroll
    for (int f = 0; f < 32; f++) acc[f] = vzero;

    const int ra = wid * 16 + (lane & 15);
    short8 af[2];
#pragma unroll
    for (int kk = 0; kk < 2; kk++)
        af[kk] = *(const short8*)((char*)y_s + ra * 128 +
                                  (((kk * 4 + (lane >> 4)) ^ (ra & 7)) << 4));
#pragma unroll
    for (int fn = 0; fn < 32; fn++) {
        const int rb = fn * 16 + (lane & 15);
#pragma unroll
        for (int kk = 0; kk < 2; kk++) {
            short8 bf = *(const short8*)((char*)wp_s + rb * 128 +
                                         (((kk * 4 + (lane >> 4)) ^ (rb & 7)) << 4));
            acc[fn] = __builtin_amdgcn_mfma_f32_16x16x32_bf16(af[kk], bf, acc[fn], 0, 0, 0);
        }
    }
    __syncthreads();   // all waves done reading y_s/wp_s

    // --- cooperative bounce: 2 chunks of 64 rows x 256 cols, stride 260 ---
    const int g  = lane >> 4;
    const int cc = lane & 15;
    float4 bb01[2];
    bb01[0] = *(const float4*)&bp[lane * 4];
    bb01[1] = *(const float4*)&bp[256 + lane * 4];

#pragma unroll
    for (int ch = 0; ch < 2; ch++) {
        if (ch) __syncthreads();   // WAR: chunk-0 reads done before overwrite
        // write: wave's own 16 rows; banks 2-way (free)
#pragma unroll
        for (int f = 0; f < 16; f++)
#pragma unroll
            for (int r = 0; r < 4; r++)
                st[(wid * 16 + g * 4 + r) * 260 + f * 16 + cc] = acc[ch * 16 + f][r];
        __syncthreads();
        // read: one full row (1KB) per wave-instruction, contiguous stores
        const float4 bb = bb01[ch];
#pragma unroll
        for (int it = 0; it < 16; it++) {
            const int row = it * 4 + wid;
            float4 v = *(const float4*)&st[row * 260 + lane * 4];
            float4 o = {v.x + bb.x, v.y + bb.y, v.z + bb.z, v.w + bb.w};
            const size_t obase = ((size_t)b * T_ + t0 + row) * DIM_ + ch * 256 + lane * 4;
            *(float4*)&out[obase] = o;
            if (write_both)
                *(float4*)&out[SZ_COPY + obase] = o;
        }
    }
}

__global__ void dup_kernel(const float4* __restrict__ src, float4* __restrict__ dst, int n4)
{
    int idx = blockIdx.x * blockDim.x + threadIdx.x;
    int stride = gridDim.x * blockDim.x;
    for (int k = idx; k < n4; k += stride) dst[k] = src[k];
}

extern "C" void kernel_launch(void* const* d_in, const int* in_sizes, int n_in,
                              void* d_out, int out_size, void* d_ws, size_t ws_size,
                              hipStream_t stream)
{
    const float* x     = (const float*)d_in[0];
    const float* wq    = (const float*)d_in[1];
    const float* bq    = (const float*)d_in[2];
    const float* wk    = (const float*)d_in[3];
    const float* bk    = (const float*)d_in[4];
    const float* wv    = (const float*)d_in[5];
    const float* bv    = (const float*)d_in[6];
    const float* wp    = (const float*)d_in[7];
    const float* bp    = (const float*)d_in[8];
    const float* wbias = (const float*)d_in[9];
    float* out = (float*)d_out;

    const size_t SZ_COPY = (size_t)B_ * T_ * DIM_;

    // scratch layout (bytes):
    //   Aexp   bf16 [4096][4096]            33,554,432 @ 0
    //   xT/ND  bf16 chunk / [2][4096][1024] 16,777,216 @ 33,554,432 (aliased)
    //   SbT    bf16 [1024][4096]             8,388,608 @ 50,331,648
    //   Qbuf   bf16 [8][4096][64]            4,194,304 @ 58,720,256
    //   Wcat   bf16 [192][512]                 196,608 @ 62,914,560
    //   wpb    bf16 [512][64]                   65,536 @ 63,111,168
    //   bcat   f32  [192]                          768 @ 63,176,704
    const size_t NEED = 63177472;
    char* R;
    int write_both;
    if (ws_size >= NEED) {
        R = (char*)d_ws;
        write_both = 1;
    } else {
        R = (char*)(out + SZ_COPY);
        write_both = 0;
    }
    unsigned short* Aexp  = (unsigned short*)R;
    unsigned short* xT    = (unsigned short*)(R + 33554432);
    unsigned short* NDbuf = (unsigned short*)(R + 33554432);
    unsigned short* SbT   = (unsigned short*)(R + 50331648);
    unsigned short* Qbuf  = (unsigned short*)(R + 58720256);
    unsigned short* Wcat  = (unsigned short*)(R + 62914560);
    unsigned short* wpb   = (unsigned short*)(R + 63111168);
    float*          bcat  = (float*)(R + 63176704);

    ewb_kernel<<<2048, 256, 0, stream>>>(wbias, Aexp);
    wcat_kernel<<<192, 128, 0, stream>>>(wq, bq, wk, bk, wv, bv, Wcat, bcat);
    wpb_kernel<<<32, 256, 0, stream>>>(wp, wpb);
    for (int chunk = 0; chunk < 2; chunk++) {
        const int b0 = chunk * 4;
        xpose_kernel<<<dim3(T_ / 64, DIM_ / 64, 4), 256, 0, stream>>>(x, xT, b0);
        qkv_mfma<<<dim3(T_ / 64, 4), 256, 0, stream>>>(xT, Wcat, bcat, Qbuf, SbT, b0);
    }
    aft_gemm_mfma<<<dim3(NC_ / 128, T_ / 128, 2), 256, 0, stream>>>(Aexp, SbT, NDbuf);
    epilogue_mfma<<<dim3(T_ / 64, B_), 256, 0, stream>>>(Qbuf, NDbuf, wpb, bp, out, write_both);
    if (!write_both)
        dup_kernel<<<2048, 256, 0, stream>>>((const float4*)out,
                                             (float4*)(out + SZ_COPY),
                                             (int)(SZ_COPY / 4));
}

// Round 7
// 149.921 us; speedup vs baseline: 4.4120x; 1.0886x over previous
//
#include <hip/hip_runtime.h>
#include <hip/hip_bf16.h>

#define B_   8
#define DIM_ 512
#define T_   4096
#define H_   64
#define NC_  1024   // 2*B*H : cols 0..511 = eK*V (c=b*64+h), 512..1023 = eK

typedef __attribute__((ext_vector_type(8))) short short8;
typedef __attribute__((ext_vector_type(4))) float f32x4;

__device__ __forceinline__ unsigned short f2bf(float x) {
    __hip_bfloat16 h = __float2bfloat16(x);
    return *reinterpret_cast<unsigned short*>(&h);
}
__device__ __forceinline__ float bf2f(unsigned short u) {
    __hip_bfloat16 h = *reinterpret_cast<__hip_bfloat16*>(&u);
    return __bfloat162float(h);
}
__device__ __forceinline__ void gload16(const void* g, void* l) {
    __builtin_amdgcn_global_load_lds(
        (const __attribute__((address_space(1))) unsigned int*)g,
        (__attribute__((address_space(3))) unsigned int*)l, 16, 0, 0);
}

// ---------------------------------------------------------------------------
// K0: Aexp[t][s] = bf16(exp(wbias[t][s]))
// ---------------------------------------------------------------------------
__global__ __launch_bounds__(256) void ewb_kernel(
    const float* __restrict__ wb, unsigned short* __restrict__ Aexp)
{
    const int n4 = T_ * T_ / 4;
    int idx = blockIdx.x * blockDim.x + threadIdx.x;
    int stride = gridDim.x * blockDim.x;
    for (int i = idx; i < n4; i += stride) {
        float4 v = ((const float4*)wb)[i];
        ushort4 o;
        o.x = f2bf(__expf(v.x));
        o.y = f2bf(__expf(v.y));
        o.z = f2bf(__expf(v.z));
        o.w = f2bf(__expf(v.w));
        ((ushort4*)Aexp)[i] = o;
    }
}

// ---------------------------------------------------------------------------
// K0b: Wcat[192][512] bf16 from {wq,wk,wv}; bcat[192] f32 from {bq,bk,bv}.
// ---------------------------------------------------------------------------
__global__ __launch_bounds__(128) void wcat_kernel(
    const float* __restrict__ wq, const float* __restrict__ bq,
    const float* __restrict__ wk, const float* __restrict__ bk,
    const float* __restrict__ wv, const float* __restrict__ bv,
    unsigned short* __restrict__ Wcat, float* __restrict__ bcat)
{
    const int r = blockIdx.x;
    const int tid = threadIdx.x;
    const float* src = (r < 64) ? (wq + (size_t)r * DIM_)
                     : (r < 128) ? (wk + (size_t)(r - 64) * DIM_)
                                 : (wv + (size_t)(r - 128) * DIM_);
    const int d4 = tid * 4;
    float4 v = *(const float4*)&src[d4];
    ushort4 o;
    o.x = f2bf(v.x); o.y = f2bf(v.y); o.z = f2bf(v.z); o.w = f2bf(v.w);
    *(ushort4*)&Wcat[(size_t)r * DIM_ + d4] = o;
    if (tid == 0)
        bcat[r] = (r < 64) ? bq[r] : (r < 128) ? bk[r - 64] : bv[r - 128];
}

// ---------------------------------------------------------------------------
// K0c: wpb[512][64] bf16 from wp.
// ---------------------------------------------------------------------------
__global__ __launch_bounds__(256) void wpb_kernel(
    const float* __restrict__ wp, unsigned short* __restrict__ wpb)
{
    const int i = (blockIdx.x * 256 + threadIdx.x) * 4;
    float4 v = *(const float4*)&wp[i];
    ushort4 o;
    o.x = f2bf(v.x); o.y = f2bf(v.y); o.z = f2bf(v.z); o.w = f2bf(v.w);
    *(ushort4*)&wpb[i] = o;
}

// ---------------------------------------------------------------------------
// K1: fused transpose + QKV via MFMA.  grid (T/64, B), block 256 (4 waves).
// Stages x[b][d0:d0+64][t0:t0+64] f32 into padded LDS [d][t] (stride 65),
// assembles A-frags by transposed column reads + f2bf (<=2-way banks, free).
// C[t][h'] = sum_d x[d][t] * Wcat[h'][d]; h' 0..63 Q, 64..127 K, 128..191 V.
// Writes Qb bf16 [b][t][64], SbT bf16 [c][t].  x read exactly once.
// ---------------------------------------------------------------------------
__global__ __launch_bounds__(256) void xqkv_fused(
    const float* __restrict__ x, const unsigned short* __restrict__ Wcat,
    const float* __restrict__ bcat,
    unsigned short* __restrict__ Qb, unsigned short* __restrict__ SbT)
{
    __shared__ float xs[64 * 65];             // [d][t] f32, 16.6 KB
    __shared__ unsigned short Bs[192 * 64];   // [h][d] bf16, 24 KB

    const int tid = threadIdx.x;
    const int t0 = blockIdx.x * 64;
    const int b  = blockIdx.y;
    const int wid = tid >> 6, lane = tid & 63;

    f32x4 acc[12];
    const f32x4 vzero = {0.f, 0.f, 0.f, 0.f};
#pragma unroll
    for (int f = 0; f < 12; f++) acc[f] = vzero;

    const int rs  = tid >> 3;        // Bs staging row 0..31
    const int ks8 = (tid & 7) * 8;
    const unsigned short* Bg = Wcat + (size_t)rs * DIM_ + ks8;

    const int xrow = tid >> 4;       // x staging: d-row 0..15 (+p*16)
    const int xt4  = (tid & 15) * 4;

    const int t_in = lane & 15;
    const int g    = lane >> 4;

    for (int d0 = 0; d0 < DIM_; d0 += 64) {
        // stage x f32 tile (coalesced 256B rows)
#pragma unroll
        for (int p = 0; p < 4; p++) {
            const int d = p * 16 + xrow;
            float4 v = *(const float4*)&x[((size_t)b * DIM_ + d0 + d) * T_ + t0 + xt4];
            *(float4*)&xs[d * 65 + xt4] = v;
        }
        // stage Wcat k-slice via async global->LDS
#pragma unroll
        for (int it = 0; it < 6; it++)
            gload16(Bg + (size_t)(it * 32) * DIM_ + d0, (void*)&Bs[(it * 256 + tid) * 8]);
        __syncthreads();

        const int row_a = wid * 16 + t_in;   // t within tile
#pragma unroll
        for (int kk = 0; kk < 2; kk++) {
            union { unsigned short s[8]; short8 v; } af;
#pragma unroll
            for (int j = 0; j < 8; j++)
                af.s[j] = f2bf(xs[(kk * 32 + g * 8 + j) * 65 + row_a]);
            const int kr = kk * 32 + g * 8;
#pragma unroll
            for (int fn = 0; fn < 12; fn++) {
                short8 bf = *(const short8*)&Bs[(fn * 16 + t_in) * 64 + kr];
                acc[fn] = __builtin_amdgcn_mfma_f32_16x16x32_bf16(af.v, bf, acc[fn], 0, 0, 0);
            }
        }
        __syncthreads();
    }

    const int cc = t_in;
    const int t_base = t0 + wid * 16 + g * 4;

    // Q (fn 0..3) -> Qb bf16
#pragma unroll
    for (int fn = 0; fn < 4; fn++) {
        const int h = fn * 16 + cc;
        const float bb = bcat[h];
#pragma unroll
        for (int r = 0; r < 4; r++)
            Qb[((size_t)b * T_ + t_base + r) * H_ + h] = f2bf(acc[fn][r] + bb);
    }
    // K (fn 4..7) + V (fn 8..11) -> SbT
#pragma unroll
    for (int f = 0; f < 4; f++) {
        const int h = f * 16 + cc;
        const float bK = bcat[64 + h];
        const float bV = bcat[128 + h];
        ushort4 pk, pe;
        float e0 = __expf(acc[4 + f][0] + bK), v0 = acc[8 + f][0] + bV;
        float e1 = __expf(acc[4 + f][1] + bK), v1 = acc[8 + f][1] + bV;
        float e2 = __expf(acc[4 + f][2] + bK), v2 = acc[8 + f][2] + bV;
        float e3 = __expf(acc[4 + f][3] + bK), v3 = acc[8 + f][3] + bV;
        pe.x = f2bf(e0); pe.y = f2bf(e1); pe.z = f2bf(e2); pe.w = f2bf(e3);
        pk.x = f2bf(e0 * v0); pk.y = f2bf(e1 * v1); pk.z = f2bf(e2 * v2); pk.w = f2bf(e3 * v3);
        *(ushort4*)&SbT[(size_t)(b * 64 + h) * T_ + t_base] = pk;
        *(ushort4*)&SbT[(size_t)(512 + b * 64 + h) * T_ + t_base] = pe;
    }
}

// ---------------------------------------------------------------------------
// K2: ND[ks][t][c] = sum_{s in half ks} Aexp[t][s] * SbT[c][s]   (bf16 MFMA)
// 128x128 tile, BK=64, split-K=2.  XCD-aware bijective swizzle (512 blocks).
// ---------------------------------------------------------------------------
__global__ __launch_bounds__(256) void aft_gemm_mfma(
    const unsigned short* __restrict__ Aexp,
    const unsigned short* __restrict__ SbT,
    unsigned short* __restrict__ ND)
{
    __shared__ unsigned short As[128 * 64];   // [t'][k]
    __shared__ unsigned short Bs[128 * 64];   // [c'][k]

    const int tid = threadIdx.x;
    const int lin = blockIdx.x + (blockIdx.y << 3) + (blockIdx.z << 8); // 0..511
    const int swz = ((lin & 7) << 6) + (lin >> 3);                      // bijective
    const int c0 = (swz & 7) * 128;
    const int t0 = ((swz >> 3) & 31) * 128;
    const int ks = swz >> 8;
    const int sbase = ks * (T_ / 2);

    const int wid = tid >> 6, lane = tid & 63;
    const int wm = wid >> 1, wn = wid & 1;

    f32x4 acc[4][4];
    const f32x4 vzero = {0.f, 0.f, 0.f, 0.f};
#pragma unroll
    for (int a = 0; a < 4; a++)
#pragma unroll
        for (int b2 = 0; b2 < 4; b2++) acc[a][b2] = vzero;

    const int rs  = tid >> 3;
    const int ks8 = (tid & 7) * 8;
    const unsigned short* Ag = Aexp + (size_t)(t0 + rs) * T_ + sbase + ks8;
    const unsigned short* Bg = SbT  + (size_t)(c0 + rs) * T_ + sbase + ks8;

    for (int s0 = 0; s0 < T_ / 2; s0 += 64) {
#pragma unroll
        for (int it = 0; it < 4; it++) {
            gload16(Ag + (size_t)(it * 32) * T_ + s0, (void*)&As[(it * 256 + tid) * 8]);
            gload16(Bg + (size_t)(it * 32) * T_ + s0, (void*)&Bs[(it * 256 + tid) * 8]);
        }
        __syncthreads();
        const int row_a = wm * 64 + (lane & 15);
        const int row_b = wn * 64 + (lane & 15);
#pragma unroll
        for (int kk = 0; kk < 2; kk++) {
            const int kr = kk * 32 + (lane >> 4) * 8;
            short8 af[4], bfr[4];
#pragma unroll
            for (int f = 0; f < 4; f++)
                af[f] = *(const short8*)&As[(row_a + f * 16) * 64 + kr];
#pragma unroll
            for (int f = 0; f < 4; f++)
                bfr[f] = *(const short8*)&Bs[(row_b + f * 16) * 64 + kr];
#pragma unroll
            for (int fm = 0; fm < 4; fm++)
#pragma unroll
                for (int fn = 0; fn < 4; fn++)
                    acc[fm][fn] = __builtin_amdgcn_mfma_f32_16x16x32_bf16(
                        af[fm], bfr[fn], acc[fm][fn], 0, 0, 0);
        }
        __syncthreads();
    }

    unsigned short* NDp = ND + (size_t)ks * T_ * NC_;
    const int r4 = (lane >> 4) * 4;
    const int cc = lane & 15;
#pragma unroll
    for (int fm = 0; fm < 4; fm++)
#pragma unroll
        for (int fn = 0; fn < 4; fn++)
#pragma unroll
            for (int r = 0; r < 4; r++) {
                const int t = t0 + wm * 64 + fm * 16 + r4 + r;
                const int c = c0 + wn * 64 + fn * 16 + cc;
                NDp[(size_t)t * NC_ + c] = f2bf(acc[fm][fn][r]);
            }
}

// ---------------------------------------------------------------------------
// K3: epilogue via MFMA.  grid (T/64, B), block 256 (4 waves).
// y = sigmoid(Q)*num/den (bf16, XOR-swizzled LDS); out = y @ wpb.T + bp.
// C-write: cooperative 2-chunk bounce (d-halves), LDS [64][260] f32,
// barrier-ordered, fully-contiguous 1KB stores/instr.
// ---------------------------------------------------------------------------
__global__ __launch_bounds__(256) void epilogue_mfma(
    const unsigned short* __restrict__ Qb, const unsigned short* __restrict__ ND,
    const unsigned short* __restrict__ wpb, const float* __restrict__ bp,
    float* __restrict__ out, int write_both)
{
    __shared__ unsigned short smem[36864];      // 72 KB
    unsigned short* y_s  = smem;                // 8 KB, swizzled [t][h]
    unsigned short* wp_s = smem + 4096;         // 64 KB, swizzled [d][h]
    float* st = (float*)smem;                   // bounce [64][260] f32 (66.6 KB)

    const int tid  = threadIdx.x;
    const int t0   = blockIdx.x * 64;
    const int b    = blockIdx.y;
    const int wid  = tid >> 6, lane = tid & 63;
    const size_t SZ_COPY = (size_t)B_ * T_ * DIM_;

    // --- stage wpb -> wp_s: linear LDS dest, pre-swizzled global source ---
    {
        const int rs = tid >> 3;      // 0..31
        const int c8 = tid & 7;
#pragma unroll
        for (int p = 0; p < 16; p++) {
            const int row = p * 32 + rs;
            gload16(wpb + (size_t)row * 64 + ((c8 ^ (row & 7)) << 3),
                    (void*)&wp_s[((size_t)row * 8 + c8) * 8]);
        }
    }
    // --- compute y -> y_s (swizzled ds_write), overlaps with async staging ---
    {
        const int t   = tid >> 2;
        const int h16 = (tid & 3) * 16;
        const unsigned short* ND1 = ND + (size_t)T_ * NC_;
        const size_t qoff = ((size_t)b * T_ + t0 + t) * H_ + h16;
        const size_t noff = (size_t)(t0 + t) * NC_ + b * 64 + h16;
        float yv[16];
#pragma unroll
        for (int u = 0; u < 16; u++) {
            float q   = bf2f(Qb[qoff + u]);
            float num = bf2f(ND[noff + u]) + bf2f(ND1[noff + u]);
            float den = bf2f(ND[noff + 512 + u]) + bf2f(ND1[noff + 512 + u]);
            yv[u] = (1.f / (1.f + __expf(-q))) * num / den;
        }
#pragma unroll
        for (int u = 0; u < 2; u++) {
            const int h8 = (tid & 3) * 2 + u;
            union { unsigned short s[8]; short8 v; } pk;
#pragma unroll
            for (int e = 0; e < 8; e++) pk.s[e] = f2bf(yv[u * 8 + e]);
            *(short8*)((char*)y_s + t * 128 + ((h8 ^ (t & 7)) << 4)) = pk.v;
        }
    }
    __syncthreads();

    // --- MFMA: rows = t0 + wid*16 + (lane&15); 32 n-frags cover d 0..511 ---
    f32x4 acc[32];
    const f32x4 vzero = {0.f, 0.f, 0.f, 0.f};
#pragma unroll
    for (int f = 0; f < 32; f++) acc[f] = vzero;

    const int ra = wid * 16 + (lane & 15);
    short8 af[2];
#pragma unroll
    for (int kk = 0; kk < 2; kk++)
        af[kk] = *(const short8*)((char*)y_s + ra * 128 +
                                  (((kk * 4 + (lane >> 4)) ^ (ra & 7)) << 4));
#pragma unroll
    for (int fn = 0; fn < 32; fn++) {
        const int rb = fn * 16 + (lane & 15);
#pragma unroll
        for (int kk = 0; kk < 2; kk++) {
            short8 bf = *(const short8*)((char*)wp_s + rb * 128 +
                                         (((kk * 4 + (lane >> 4)) ^ (rb & 7)) << 4));
            acc[fn] = __builtin_amdgcn_mfma_f32_16x16x32_bf16(af[kk], bf, acc[fn], 0, 0, 0);
        }
    }
    __syncthreads();   // all waves done reading y_s/wp_s

    // --- cooperative bounce: 2 chunks of 64 rows x 256 cols, stride 260 ---
    const int g  = lane >> 4;
    const int cc = lane & 15;
    float4 bb01[2];
    bb01[0] = *(const float4*)&bp[lane * 4];
    bb01[1] = *(const float4*)&bp[256 + lane * 4];

#pragma unroll
    for (int ch = 0; ch < 2; ch++) {
        if (ch) __syncthreads();   // WAR: chunk-0 reads done before overwrite
#pragma unroll
        for (int f = 0; f < 16; f++)
#pragma unroll
            for (int r = 0; r < 4; r++)
                st[(wid * 16 + g * 4 + r) * 260 + f * 16 + cc] = acc[ch * 16 + f][r];
        __syncthreads();
        const float4 bb = bb01[ch];
#pragma unroll
        for (int it = 0; it < 16; it++) {
            const int row = it * 4 + wid;
            float4 v = *(const float4*)&st[row * 260 + lane * 4];
            float4 o = {v.x + bb.x, v.y + bb.y, v.z + bb.z, v.w + bb.w};
            const size_t obase = ((size_t)b * T_ + t0 + row) * DIM_ + ch * 256 + lane * 4;
            *(float4*)&out[obase] = o;
            if (write_both)
                *(float4*)&out[SZ_COPY + obase] = o;
        }
    }
}

__global__ void dup_kernel(const float4* __restrict__ src, float4* __restrict__ dst, int n4)
{
    int idx = blockIdx.x * blockDim.x + threadIdx.x;
    int stride = gridDim.x * blockDim.x;
    for (int k = idx; k < n4; k += stride) dst[k] = src[k];
}

extern "C" void kernel_launch(void* const* d_in, const int* in_sizes, int n_in,
                              void* d_out, int out_size, void* d_ws, size_t ws_size,
                              hipStream_t stream)
{
    const float* x     = (const float*)d_in[0];
    const float* wq    = (const float*)d_in[1];
    const float* bq    = (const float*)d_in[2];
    const float* wk    = (const float*)d_in[3];
    const float* bk    = (const float*)d_in[4];
    const float* wv    = (const float*)d_in[5];
    const float* bv    = (const float*)d_in[6];
    const float* wp    = (const float*)d_in[7];
    const float* bp    = (const float*)d_in[8];
    const float* wbias = (const float*)d_in[9];
    float* out = (float*)d_out;

    const size_t SZ_COPY = (size_t)B_ * T_ * DIM_;

    // scratch layout (bytes):
    //   Aexp   bf16 [4096][4096]            33,554,432 @ 0
    //   ND     bf16 [2][4096][1024]         16,777,216 @ 33,554,432
    //   SbT    bf16 [1024][4096]             8,388,608 @ 50,331,648
    //   Qbuf   bf16 [8][4096][64]            4,194,304 @ 58,720,256
    //   Wcat   bf16 [192][512]                 196,608 @ 62,914,560
    //   wpb    bf16 [512][64]                   65,536 @ 63,111,168
    //   bcat   f32  [192]                          768 @ 63,176,704
    const size_t NEED = 63177472;
    char* R;
    int write_both;
    if (ws_size >= NEED) {
        R = (char*)d_ws;
        write_both = 1;
    } else {
        R = (char*)(out + SZ_COPY);
        write_both = 0;
    }
    unsigned short* Aexp  = (unsigned short*)R;
    unsigned short* NDbuf = (unsigned short*)(R + 33554432);
    unsigned short* SbT   = (unsigned short*)(R + 50331648);
    unsigned short* Qbuf  = (unsigned short*)(R + 58720256);
    unsigned short* Wcat  = (unsigned short*)(R + 62914560);
    unsigned short* wpb   = (unsigned short*)(R + 63111168);
    float*          bcat  = (float*)(R + 63176704);

    ewb_kernel<<<2048, 256, 0, stream>>>(wbias, Aexp);
    wcat_kernel<<<192, 128, 0, stream>>>(wq, bq, wk, bk, wv, bv, Wcat, bcat);
    wpb_kernel<<<32, 256, 0, stream>>>(wp, wpb);
    xqkv_fused<<<dim3(T_ / 64, B_), 256, 0, stream>>>(x, Wcat, bcat, Qbuf, SbT);
    aft_gemm_mfma<<<dim3(NC_ / 128, T_ / 128, 2), 256, 0, stream>>>(Aexp, SbT, NDbuf);
    epilogue_mfma<<<dim3(T_ / 64, B_), 256, 0, stream>>>(Qbuf, NDbuf, wpb, bp, out, write_both);
    if (!write_both)
        dup_kernel<<<2048, 256, 0, stream>>>((const float4*)out,
                                             (float4*)(out + SZ_COPY),
                                             (int)(SZ_COPY / 4));
}